// Round 3
// baseline (5099.753 us; speedup 1.0000x reference)
//
#include <hip/hip_runtime.h>
#include <math.h>

#define NN 2048
#define NE 12288
#define NCO 49
#define NRr 29
#define CD 128
#define NG 16
#define ECHUNK 1536
#define FCHUNK 512   // nodes per FFN chunk

// RESTRICT: indices k (0..48) with |m|<=2.
// l=0:0 | l=1:1,2,3 | l=2:4..8 | l=3:10..14 | l=4:18..22 | l=5:28..32 | l=6:40..44
__constant__ int c_res[29] = {0,1,2,3,4,5,6,7,8,10,11,12,13,14,18,19,20,21,22,28,29,30,31,32,40,41,42,43,44};
__constant__ int c_rinv[49] = {0,1,2,3,4,5,6,7,8,-1,9,10,11,12,13,-1,-1,-1,14,15,16,17,18,-1,-1,-1,-1,-1,19,20,21,22,23,-1,-1,-1,-1,-1,-1,-1,24,25,26,27,28,-1,-1,-1,-1};

__device__ __forceinline__ constexpr int deg_of(int k){
  return (k<1)?0:(k<4)?1:(k<9)?2:(k<16)?3:(k<25)?4:(k<36)?5:6;
}
__device__ __forceinline__ float siluf(float x){ return x / (1.f + expf(-x)); }

// ---------------- CSR build (deterministic, no atomics) ----------------
__global__ void k_count(const int* __restrict__ dst, int* __restrict__ cnt){
  int n = blockIdx.x*blockDim.x + threadIdx.x;
  if (n >= NN) return;
  int c = 0;
  for (int e = 0; e < NE; e++) c += (dst[e] == n);
  cnt[n] = c;
}
__global__ void k_scan(const int* __restrict__ cnt, int* __restrict__ rowptr){
  int n = blockIdx.x*blockDim.x + threadIdx.x;
  if (n > NN) return;
  int s = 0;
  for (int m = 0; m < n; m++) s += cnt[m];
  rowptr[n] = s;
}
__global__ void k_fill(const int* __restrict__ dst, const int* __restrict__ rowptr, int* __restrict__ eid){
  int n = blockIdx.x*blockDim.x + threadIdx.x;
  if (n >= NN) return;
  int p = rowptr[n];
  for (int e = 0; e < NE; e++) if (dst[e] == n) eid[p++] = e;
}
__global__ void k_gstart(const int* __restrict__ batch, int* __restrict__ gs){
  int g = threadIdx.x;
  if (g > NG) return;
  int s = 0;
  for (int n = 0; n < NN; n++) s += (batch[n] < g);
  gs[g] = s;
}

// ---------------- geometry: d + real spherical harmonics ----------------
__global__ void k_geom(const float* __restrict__ ev, float* __restrict__ Y, float* __restrict__ dv){
  int e = blockIdx.x*blockDim.x + threadIdx.x;
  if (e >= NE) return;
  float x = ev[e*3+0], y = ev[e*3+1], z = ev[e*3+2];
  float r = sqrtf(x*x + y*y + z*z);
  dv[e] = r;
  float rn = fmaxf(r, 1e-8f);
  float ux = x/rn, uy = y/rn, uz = z/rn;
  float ct = fminf(fmaxf(uz, -1.f), 1.f);
  float st = sqrtf(fminf(fmaxf(1.f - ct*ct, 1e-12f), 1.f));
  float phi = atan2f(uy, ux);
  float P[7][7];
  P[0][0] = 1.f;
  #pragma unroll
  for (int m = 1; m <= 6; m++) P[m][m] = -(2.f*m - 1.f)*st*P[m-1][m-1];
  #pragma unroll
  for (int m = 0; m <= 5; m++) P[m+1][m] = (2.f*m + 1.f)*ct*P[m][m];
  #pragma unroll
  for (int m = 0; m <= 6; m++){
    #pragma unroll
    for (int l = m+2; l <= 6; l++)
      P[l][m] = ((2.f*l - 1.f)*ct*P[l-1][m] - (float)(l+m-1)*P[l-2][m]) / (float)(l-m);
  }
  float cmv[7], smv[7];
  #pragma unroll
  for (int m = 0; m <= 6; m++){ cmv[m] = cosf((float)m*phi); smv[m] = sinf((float)m*phi); }
  const double FOURPI = 12.566370614359172;
  int k = 0;
  #pragma unroll
  for (int l = 0; l <= 6; l++){
    #pragma unroll
    for (int mm = -l; mm <= l; mm++){
      int am = mm < 0 ? -mm : mm;
      double ratio = 1.0;
      for (int i = l-am+1; i <= l+am; i++) ratio /= (double)i;
      double nrm = sqrt((2.0*l + 1.0)/FOURPI*ratio);
      float v;
      if (mm == 0)      v = (float)nrm * P[l][0];
      else if (mm > 0)  v = (float)(1.4142135623730951*nrm) * P[l][am] * cmv[am];
      else              v = (float)(1.4142135623730951*nrm) * P[l][am] * smv[am];
      Y[(size_t)e*49 + k] = v; k++;
    }
  }
}

// ------------- layer-1 of radial MLPs: windowed gaussian @ W + b, silu -------------
// exp(-1794*(d-off)^2) underflows f32 beyond ~26 taps -> 64-tap window is exact.
__global__ __launch_bounds__(128) void k_rad1(const float* __restrict__ dv, const float* __restrict__ Wm,
                                              const float* __restrict__ bias, float* __restrict__ out){
  int e = blockIdx.x;
  int j = threadIdx.x;
  float d = dv[e];
  const float STEPF = (float)(5.0/599.0);
  const double step_d = (double)STEPF;
  const float GC = (float)(-0.5/((2.0*step_d)*(2.0*step_d)));
  __shared__ float g[64];
  int bc = (int)rintf(d / STEPF);
  int b0 = bc - 32;
  if (j < 64){
    int b = b0 + j;
    float gg = 0.f;
    if (b >= 0 && b < 600){
      float off = (float)((double)b * (5.0/599.0));
      float t = d - off;
      gg = expf(GC*t*t);
    }
    g[j] = gg;
  }
  __syncthreads();
  float acc = bias ? bias[j] : 0.f;
  #pragma unroll 8
  for (int i = 0; i < 64; i++){
    int b = b0 + i;
    if (b >= 0 && b < 600) acc += g[i]*Wm[b*CD + j];
  }
  out[(size_t)e*CD + j] = siluf(acc);
}

// ---------------- tiled f32 GEMM: C = act(A@B + bias), optional += ----------------
template<int ACT, int ACCUM>
__global__ __launch_bounds__(256) void k_gemm(const float* __restrict__ A, const float* __restrict__ B,
                                              const float* __restrict__ bias, float* __restrict__ C,
                                              int M, int Nc, int K){
  __shared__ float As[64][17];
  __shared__ float Bs[16][64];
  int bm = blockIdx.y*64, bn = blockIdx.x*64;
  int tid = threadIdx.x;
  int tx = tid & 15, ty = tid >> 4;
  float acc[4][4] = {{0.f,0.f,0.f,0.f},{0.f,0.f,0.f,0.f},{0.f,0.f,0.f,0.f},{0.f,0.f,0.f,0.f}};
  for (int k0 = 0; k0 < K; k0 += 16){
    #pragma unroll
    for (int i = tid; i < 1024; i += 256){
      int m = i >> 4, kk = i & 15;
      int row = bm + m;
      As[m][kk] = (row < M) ? A[(size_t)row*K + k0 + kk] : 0.f;
    }
    #pragma unroll
    for (int i = tid; i < 1024; i += 256){
      int kk = i >> 6, n = i & 63;
      Bs[kk][n] = B[(size_t)(k0 + kk)*Nc + bn + n];
    }
    __syncthreads();
    #pragma unroll
    for (int kk = 0; kk < 16; kk++){
      float a0 = As[ty*4+0][kk];
      float a1 = As[ty*4+1][kk];
      float a2 = As[ty*4+2][kk];
      float a3 = As[ty*4+3][kk];
      float4 b4 = *(const float4*)&Bs[kk][tx*4];
      acc[0][0]+=a0*b4.x; acc[0][1]+=a0*b4.y; acc[0][2]+=a0*b4.z; acc[0][3]+=a0*b4.w;
      acc[1][0]+=a1*b4.x; acc[1][1]+=a1*b4.y; acc[1][2]+=a1*b4.z; acc[1][3]+=a1*b4.w;
      acc[2][0]+=a2*b4.x; acc[2][1]+=a2*b4.y; acc[2][2]+=a2*b4.z; acc[2][3]+=a2*b4.w;
      acc[3][0]+=a3*b4.x; acc[3][1]+=a3*b4.y; acc[3][2]+=a3*b4.z; acc[3][3]+=a3*b4.w;
    }
    __syncthreads();
  }
  #pragma unroll
  for (int i = 0; i < 4; i++){
    int row = bm + ty*4 + i;
    if (row >= M) continue;
    #pragma unroll
    for (int j = 0; j < 4; j++){
      int col = bn + tx*4 + j;
      float v = acc[i][j];
      if (bias) v += bias[col];
      if (ACT == 1) v = siluf(v);
      size_t idx = (size_t)row*Nc + col;
      if (ACCUM) C[idx] += v; else C[idx] = v;
    }
  }
}

// ---------------- node init: embedding + Y (x) rad_deg scatter via CSR ----------------
__global__ __launch_bounds__(128) void k_init(const float* __restrict__ pos, const float* __restrict__ table,
                                              const float* __restrict__ Yb, const float* __restrict__ radd,
                                              const int* __restrict__ rowptr, const int* __restrict__ eid,
                                              float* __restrict__ x){
  int n = blockIdx.x;
  int c = threadIdx.x;
  const float DLO = -3.26267f;
  const float DRG = (float)(3.295396 - (-3.26267));
  float p0 = pos[n*3+0], p1 = pos[n*3+1], p2 = pos[n*3+2];
  int t0 = min(127, max(0, (int)rintf((p0 - DLO)/DRG*128.f - 0.5f)));
  int t1 = min(127, max(0, (int)rintf((p1 - DLO)/DRG*128.f - 0.5f)));
  int t2 = min(127, max(0, (int)rintf((p2 - DLO)/DRG*128.f - 0.5f)));
  float emb = table[t0*CD + c] + table[t1*CD + c] + table[t2*CD + c];
  __shared__ float Yl[49];
  __shared__ float rl[896];
  float acc[NCO];
  #pragma unroll
  for (int k = 0; k < NCO; k++) acc[k] = 0.f;
  int pA = rowptr[n], pB = rowptr[n+1];
  for (int p = pA; p < pB; p++){
    int e = eid[p];
    if (c < 49) Yl[c] = Yb[(size_t)e*49 + c];
    #pragma unroll
    for (int q = 0; q < 7; q++) rl[q*128 + c] = radd[(size_t)e*896 + q*128 + c];
    __syncthreads();
    #pragma unroll
    for (int k = 0; k < NCO; k++){
      acc[k] += Yl[k]*rl[deg_of(k)*128 + c];
    }
    __syncthreads();
  }
  size_t base = (size_t)n*NCO*CD;
  x[base + c] = emb + acc[0]*(1.f/3.f);
  #pragma unroll
  for (int k = 1; k < NCO; k++) x[base + k*CD + c] = acc[k]*(1.f/3.f);
}

// ---------------- degree-grouped RMS norm ----------------
__global__ __launch_bounds__(128) void k_rmsnorm(const float* __restrict__ x, const float* __restrict__ w,
                                                 float* __restrict__ out){
  int n = blockIdx.x;
  int c = threadIdx.x;
  const float* xb = x + (size_t)n*NCO*CD;
  float vals[NCO];
  float ss[7] = {0,0,0,0,0,0,0};
  #pragma unroll
  for (int k = 0; k < NCO; k++){
    float v = xb[k*CD + c];
    vals[k] = v;
    ss[deg_of(k)] += v*v;
  }
  __shared__ float red[7][128];
  #pragma unroll
  for (int l = 0; l < 7; l++) red[l][c] = ss[l];
  __syncthreads();
  __shared__ float inv[7];
  if (c < 7){
    float s = 0.f;
    for (int i = 0; i < 128; i++) s += red[c][i];
    float ms = s / ((float)(2*c + 1)*128.f);
    inv[c] = 1.f / sqrtf(ms + 1e-6f);
  }
  __syncthreads();
  size_t base = (size_t)n*NCO*CD;
  #pragma unroll
  for (int k = 0; k < NCO; k++){
    int l = deg_of(k);
    out[base + k*CD + c] = vals[k]*inv[l]*w[l*CD + c];
  }
}

// ---------------- gather restricted rows / scatter-add back ----------------
__global__ void k_gather(const float* __restrict__ h, float* __restrict__ hr){
  int i = blockIdx.x*blockDim.x + threadIdx.x;
  if (i >= NN*NRr*CD) return;
  int c = i & 127;
  int kr = (i >> 7) % 29;
  int n = i / (29*128);
  hr[i] = h[((size_t)n*49 + c_res[kr])*128 + c];
}
__global__ void k_scatadd(const float* __restrict__ orr, float* __restrict__ x){
  int i = blockIdx.x*blockDim.x + threadIdx.x;
  if (i >= NN*NRr*CD) return;
  int c = i & 127;
  int kr = (i >> 7) % 29;
  int n = i / (29*128);
  x[((size_t)n*49 + c_res[kr])*128 + c] += orr[i];
}

// ---------------- attention small kernels ----------------
__global__ void k_logits(const float* __restrict__ XS, const float* __restrict__ XT,
                         const float* __restrict__ rad, const float* __restrict__ avec,
                         const int* __restrict__ src, const int* __restrict__ dst,
                         float* __restrict__ lg){
  int idx = blockIdx.x*blockDim.x + threadIdx.x;
  if (idx >= NE*8) return;
  int e = idx >> 3, hh = idx & 7;
  int s = src[e], t = dst[e];
  float acc = 0.f;
  #pragma unroll
  for (int dd = 0; dd < 16; dd++){
    int j = hh*16 + dd;
    float m = (XS[(size_t)s*NRr*CD + j] + XT[(size_t)t*NRr*CD + j]) * rad[(size_t)e*CD + j];
    acc += siluf(m)*avec[hh*16 + dd];
  }
  lg[idx] = acc;
}
__global__ void k_softmax(const float* __restrict__ lg, const int* __restrict__ rowptr,
                          const int* __restrict__ eid, float* __restrict__ mx, float* __restrict__ den){
  int idx = blockIdx.x*blockDim.x + threadIdx.x;
  if (idx >= NN*8) return;
  int n = idx >> 3, hh = idx & 7;
  int p0 = rowptr[n], p1 = rowptr[n+1];
  float m = -1e30f;
  for (int p = p0; p < p1; p++) m = fmaxf(m, lg[eid[p]*8 + hh]);
  float s = 0.f;
  for (int p = p0; p < p1; p++) s += expf(lg[eid[p]*8 + hh] - m);
  mx[idx] = m; den[idx] = s;
}
__global__ void k_alpha(const float* __restrict__ lg, const float* __restrict__ mx,
                        const float* __restrict__ den, const int* __restrict__ dst,
                        float* __restrict__ al){
  int idx = blockIdx.x*blockDim.x + threadIdx.x;
  if (idx >= NE*8) return;
  int e = idx >> 3, hh = idx & 7;
  int t = dst[e];
  al[idx] = expf(lg[idx] - mx[t*8 + hh]) / fmaxf(den[t*8 + hh], 1e-9f);
}
__global__ __launch_bounds__(128) void k_msg(const float* __restrict__ XS, const float* __restrict__ XT,
                                             const float* __restrict__ rad, const int* __restrict__ src,
                                             const int* __restrict__ dst, int e0, float* __restrict__ msgR){
  int e = e0 + blockIdx.x;
  int k = blockIdx.y;
  int c = threadIdx.x;
  int s = src[e], t = dst[e];
  float v = (XS[((size_t)s*NRr + k)*CD + c] + XT[((size_t)t*NRr + k)*CD + c]) * rad[(size_t)e*CD + c];
  msgR[((size_t)(e - e0)*NRr + k)*CD + c] = v;
}
__global__ __launch_bounds__(128) void k_agg(const float* __restrict__ V, const float* __restrict__ al,
                                             const int* __restrict__ rowptr, const int* __restrict__ eid,
                                             int e0, int e1, int first, float* __restrict__ agg){
  int n = blockIdx.x;
  int k = blockIdx.y;
  int c = threadIdx.x;
  size_t oidx = ((size_t)n*NRr + k)*CD + c;
  float s = first ? 0.f : agg[oidx];
  int hh = c >> 4;
  int p0 = rowptr[n], p1 = rowptr[n+1];
  for (int p = p0; p < p1; p++){
    int e = eid[p];
    if (e < e0 || e >= e1) continue;
    s += al[e*8 + hh]*V[((size_t)(e - e0)*NRr + k)*CD + c];
  }
  agg[oidx] = s;
}

// ---------------- FFN gating (per node chunk) ----------------
__global__ void k_gate(float* __restrict__ f1, int nnodes){
  int i = blockIdx.x*blockDim.x + threadIdx.x;
  if (i >= nnodes*512) return;
  int n = i >> 9, f = i & 511;
  size_t base = (size_t)n*49*512 + f;
  float s = f1[base];
  float sg = 1.f/(1.f + expf(-s));
  f1[base] = s*sg;
  for (int k = 1; k < 49; k++){
    size_t id = base + (size_t)k*512;
    f1[id] = f1[id]*sg;
  }
}

// ---------------- pooling ----------------
__global__ void k_pool(const float* __restrict__ orr, const int* __restrict__ gs, float* __restrict__ out){
  int i = blockIdx.x*blockDim.x + threadIdx.x;
  if (i >= NG*NCO*CD) return;
  int c = i & 127;
  int k = (i >> 7) % 49;
  int g = i / (49*128);
  int kr = c_rinv[k];
  float v = 0.f;
  if (kr >= 0){
    int a = gs[g], b = gs[g+1];
    float s = 0.f;
    for (int n = a; n < b; n++) s += orr[((size_t)n*29 + kr)*128 + c];
    int cnt = b - a;
    v = s / (float)(cnt > 0 ? cnt : 1);
  }
  out[i] = v;
}

extern "C" void kernel_launch(void* const* d_in, const int* in_sizes, int n_in,
                              void* d_out, int out_size, void* d_ws, size_t ws_size,
                              hipStream_t stream){
  const float* pos    = (const float*)d_in[0];
  const float* evec   = (const float*)d_in[1];
  const int*   eidx   = (const int*)  d_in[2];
  const int*   batch  = (const int*)  d_in[3];
  const float* table  = (const float*)d_in[4];
  const float* deg_w1 = (const float*)d_in[5];
  const float* deg_b1 = (const float*)d_in[6];
  const float* deg_w2 = (const float*)d_in[7];
  const float* deg_b2 = (const float*)d_in[8];
  const float* deg_w3 = (const float*)d_in[9];
  const float* attn_nw= (const float*)d_in[10];
  const float* w_src  = (const float*)d_in[11];
  const float* w_tgt  = (const float*)d_in[12];
  const float* rad_w1 = (const float*)d_in[13];
  const float* rad_b1 = (const float*)d_in[14];
  const float* rad_w2 = (const float*)d_in[15];
  const float* avec   = (const float*)d_in[16];
  const float* w_val  = (const float*)d_in[17];
  const float* w_proj = (const float*)d_in[18];
  const float* ffn_nw = (const float*)d_in[19];
  const float* ffn_w1 = (const float*)d_in[20];
  const float* ffn_w2 = (const float*)d_in[21];
  const float* fin_nw = (const float*)d_in[22];
  const float* lw_src = (const float*)d_in[23];
  const float* lw_tgt = (const float*)d_in[24];
  const float* lrad_w1= (const float*)d_in[25];
  const float* lrad_b1= (const float*)d_in[26];
  const float* lrad_w2= (const float*)d_in[27];
  const float* lavec  = (const float*)d_in[28];
  const float* lw_val = (const float*)d_in[29];
  const float* lw_proj= (const float*)d_in[30];

  const int* srcp = eidx;
  const int* dstp = eidx + NE;

  float* W = (float*)d_ws;
  size_t o = 0;
  float* X   = W + o; o += (size_t)NN*49*128;   // 12,845,056
  float* Hb  = W + o; o += (size_t)NN*49*128;   // 12,845,056 (also msg/V chunks, proj out)
  float* HR  = W + o; o += (size_t)NN*29*128;   // 7,602,176  (also agg)
  float* XSb = W + o; o += (size_t)NN*29*128;   // 7,602,176  (also rad_deg part 1, ffn f1 chunk part 1)
  float* XTb = W + o; o += (size_t)NN*29*128;   // 7,602,176  (spill region for rad_deg / f1 chunk)
  float* R1  = W + o; o += (size_t)NE*128;
  float* R2  = W + o; o += (size_t)NE*128;
  float* Yb  = W + o; o += (size_t)NE*49;
  float* DV  = W + o; o += (size_t)NE;
  float* LG  = W + o; o += (size_t)NE*8;
  float* AL  = W + o; o += (size_t)NE*8;
  float* MX  = W + o; o += (size_t)NN*8;
  float* DEN = W + o; o += (size_t)NN*8;
  int* CNT = (int*)(W + o); o += NN;
  int* RP  = (int*)(W + o); o += NN + 1;
  int* EID = (int*)(W + o); o += NE;
  int* GS  = (int*)(W + o); o += NG + 1;
  (void)DEN; (void)ws_size; (void)in_sizes; (void)n_in; (void)out_size;

  // aliases (lifetimes disjoint from their hosts' primary use):
  float* RADD = XSb;                              // E*896 = 11.0M <= XSb+XTb (15.2M)
  float* F1CH = XSb;                              // FCHUNK*49*512 = 12.85M <= XSb+XTb (15.2M)
  float* MSG  = Hb;                               // ECHUNK*29*128 = 5.70M
  float* VCH  = Hb + (size_t)ECHUNK*29*128;       // 5.70M  (MSG+VCH = 11.4M <= Hb 12.8M)
  float* AG   = HR;
  float* OR_  = Hb;

  // CSR + groups
  k_count<<<8, 256, 0, stream>>>(dstp, CNT);
  k_scan<<<9, 256, 0, stream>>>(CNT, RP);
  k_fill<<<8, 256, 0, stream>>>(dstp, RP, EID);
  k_gstart<<<1, 32, 0, stream>>>(batch, GS);

  // geometry
  k_geom<<<48, 256, 0, stream>>>(evec, Yb, DV);

  // degree embedding MLP: 600->128 (silu) -> 128 (silu) -> 896
  k_rad1<<<NE, 128, 0, stream>>>(DV, deg_w1, deg_b1, R1);
  k_gemm<1,0><<<dim3(2, NE/64), 256, 0, stream>>>(R1, deg_w2, deg_b2, R2, NE, 128, 128);
  k_gemm<0,0><<<dim3(14, NE/64), 256, 0, stream>>>(R2, deg_w3, nullptr, RADD, NE, 896, 128);
  k_init<<<NN, 128, 0, stream>>>(pos, table, Yb, RADD, RP, EID, X);

  for (int i = 0; i < 3; i++){
    const float* nw  = (i < 2) ? attn_nw + (size_t)i*896   : fin_nw;
    const float* ws_ = (i < 2) ? w_src  + (size_t)i*16384 : lw_src;
    const float* wt_ = (i < 2) ? w_tgt  + (size_t)i*16384 : lw_tgt;
    const float* rw1 = (i < 2) ? rad_w1 + (size_t)i*76800 : lrad_w1;
    const float* rb1 = (i < 2) ? rad_b1 + (size_t)i*128   : lrad_b1;
    const float* rw2 = (i < 2) ? rad_w2 + (size_t)i*16384 : lrad_w2;
    const float* av  = (i < 2) ? avec   + (size_t)i*128   : lavec;
    const float* wv  = (i < 2) ? w_val  + (size_t)i*16384 : lw_val;
    const float* wp  = (i < 2) ? w_proj + (size_t)i*16384 : lw_proj;

    k_rmsnorm<<<NN, 128, 0, stream>>>(X, nw, Hb);
    k_gather<<<(NN*NRr*CD + 255)/256, 256, 0, stream>>>(Hb, HR);
    k_gemm<0,0><<<dim3(2, NN*NRr/64), 256, 0, stream>>>(HR, ws_, nullptr, XSb, NN*NRr, 128, 128);
    k_gemm<0,0><<<dim3(2, NN*NRr/64), 256, 0, stream>>>(HR, wt_, nullptr, XTb, NN*NRr, 128, 128);
    k_rad1<<<NE, 128, 0, stream>>>(DV, rw1, rb1, R1);
    k_gemm<0,0><<<dim3(2, NE/64), 256, 0, stream>>>(R1, rw2, nullptr, R2, NE, 128, 128);
    k_logits<<<(NE*8 + 255)/256, 256, 0, stream>>>(XSb, XTb, R2, av, srcp, dstp, LG);
    k_softmax<<<(NN*8 + 255)/256, 256, 0, stream>>>(LG, RP, EID, MX, DEN);
    k_alpha<<<(NE*8 + 255)/256, 256, 0, stream>>>(LG, MX, DEN, dstp, AL);
    for (int ch = 0; ch < NE/ECHUNK; ch++){
      int e0 = ch*ECHUNK;
      k_msg<<<dim3(ECHUNK, NRr), 128, 0, stream>>>(XSb, XTb, R2, srcp, dstp, e0, MSG);
      k_gemm<0,0><<<dim3(2, ECHUNK*NRr/64), 256, 0, stream>>>(MSG, wv, nullptr, VCH, ECHUNK*NRr, 128, 128);
      k_agg<<<dim3(NN, NRr), 128, 0, stream>>>(VCH, AL, RP, EID, e0, e0 + ECHUNK, ch == 0, AG);
    }
    k_gemm<0,0><<<dim3(2, NN*NRr/64), 256, 0, stream>>>(AG, wp, nullptr, OR_, NN*NRr, 128, 128);
    if (i < 2){
      k_scatadd<<<(NN*NRr*CD + 255)/256, 256, 0, stream>>>(OR_, X);
      // FFN (chunked over nodes so hidden fits in XSb+XTb)
      k_rmsnorm<<<NN, 128, 0, stream>>>(X, ffn_nw + (size_t)i*896, Hb);
      for (int n0 = 0; n0 < NN; n0 += FCHUNK){
        const float* hA = Hb + (size_t)n0*NCO*CD;
        float* xC = X + (size_t)n0*NCO*CD;
        k_gemm<0,0><<<dim3(8, FCHUNK*NCO/64), 256, 0, stream>>>(hA, ffn_w1 + (size_t)i*65536, nullptr, F1CH, FCHUNK*NCO, 512, 128);
        k_gate<<<(FCHUNK*512 + 255)/256, 256, 0, stream>>>(F1CH, FCHUNK);
        k_gemm<0,1><<<dim3(2, FCHUNK*NCO/64), 256, 0, stream>>>(F1CH, ffn_w2 + (size_t)i*65536, nullptr, xC, FCHUNK*NCO, 128, 512);
      }
    } else {
      k_pool<<<(NG*NCO*CD + 255)/256, 256, 0, stream>>>(OR_, GS, (float*)d_out);
    }
  }
}

// Round 4
// 4320.729 us; speedup vs baseline: 1.1803x; 1.1803x over previous
//
#include <hip/hip_runtime.h>
#include <math.h>

#define NN 2048
#define NE 12288
#define NCO 49
#define NRr 29
#define CD 128
#define NG 16
#define ECHUNK 1536
#define FCHUNK 512   // nodes per FFN chunk

// RESTRICT: indices k (0..48) with |m|<=2.
// l=0:0 | l=1:1,2,3 | l=2:4..8 | l=3:10..14 | l=4:18..22 | l=5:28..32 | l=6:40..44
__constant__ int c_res[29] = {0,1,2,3,4,5,6,7,8,10,11,12,13,14,18,19,20,21,22,28,29,30,31,32,40,41,42,43,44};
__constant__ int c_rinv[49] = {0,1,2,3,4,5,6,7,8,-1,9,10,11,12,13,-1,-1,-1,14,15,16,17,18,-1,-1,-1,-1,-1,19,20,21,22,23,-1,-1,-1,-1,-1,-1,-1,24,25,26,27,28,-1,-1,-1,-1};

__device__ __forceinline__ constexpr int deg_of(int k){
  return (k<1)?0:(k<4)?1:(k<9)?2:(k<16)?3:(k<25)?4:(k<36)?5:6;
}
__device__ __forceinline__ float siluf(float x){ return x / (1.f + expf(-x)); }

// ---------------- CSR build (deterministic, parallel) ----------------
__global__ __launch_bounds__(1024) void k_hist(const int* __restrict__ dst, int* __restrict__ cnt){
  __shared__ int h[NN];
  for (int i = threadIdx.x; i < NN; i += 1024) h[i] = 0;
  __syncthreads();
  for (int e = threadIdx.x; e < NE; e += 1024) atomicAdd(&h[dst[e]], 1);
  __syncthreads();
  for (int i = threadIdx.x; i < NN; i += 1024) cnt[i] = h[i];
}
__global__ __launch_bounds__(1024) void k_scan2(const int* __restrict__ cnt, int* __restrict__ rowptr){
  __shared__ int a[NN], b[NN];
  int t = threadIdx.x;
  for (int i = t; i < NN; i += 1024) a[i] = cnt[i];
  __syncthreads();
  int* pin = a; int* pout = b;
  for (int off = 1; off < NN; off <<= 1){
    for (int i = t; i < NN; i += 1024)
      pout[i] = pin[i] + ((i >= off) ? pin[i - off] : 0);
    __syncthreads();
    int* tmp = pin; pin = pout; pout = tmp;
  }
  for (int i = t; i < NN; i += 1024) rowptr[i + 1] = pin[i];
  if (t == 0) rowptr[0] = 0;
}
// one wave per node; ballot+prefix-popcount keeps increasing-e order (matches segment_sum order)
__global__ __launch_bounds__(256) void k_fillw(const int* __restrict__ dst, const int* __restrict__ rowptr,
                                               int* __restrict__ eid){
  int wave = threadIdx.x >> 6;
  int lane = threadIdx.x & 63;
  int n = blockIdx.x*4 + wave;
  if (n >= NN) return;
  int base = rowptr[n];
  for (int e0 = 0; e0 < NE; e0 += 64){   // NE % 64 == 0
    int e = e0 + lane;
    bool m = (dst[e] == n);
    unsigned long long mask = __ballot(m);
    if (m){
      int pos = base + __popcll(mask & ((1ull << lane) - 1ull));
      eid[pos] = e;
    }
    base += __popcll(mask);
  }
}
__global__ void k_gstart(const int* __restrict__ batch, int* __restrict__ gs){
  int g = threadIdx.x;
  if (g > NG) return;
  int s = 0;
  for (int n = 0; n < NN; n++) s += (batch[n] < g);
  gs[g] = s;
}

// ---------------- geometry: d + real spherical harmonics ----------------
__global__ void k_geom(const float* __restrict__ ev, float* __restrict__ Y, float* __restrict__ dv){
  int e = blockIdx.x*blockDim.x + threadIdx.x;
  if (e >= NE) return;
  float x = ev[e*3+0], y = ev[e*3+1], z = ev[e*3+2];
  float r = sqrtf(x*x + y*y + z*z);
  dv[e] = r;
  float rn = fmaxf(r, 1e-8f);
  float ux = x/rn, uy = y/rn, uz = z/rn;
  float ct = fminf(fmaxf(uz, -1.f), 1.f);
  float st = sqrtf(fminf(fmaxf(1.f - ct*ct, 1e-12f), 1.f));
  float phi = atan2f(uy, ux);
  float P[7][7];
  P[0][0] = 1.f;
  #pragma unroll
  for (int m = 1; m <= 6; m++) P[m][m] = -(2.f*m - 1.f)*st*P[m-1][m-1];
  #pragma unroll
  for (int m = 0; m <= 5; m++) P[m+1][m] = (2.f*m + 1.f)*ct*P[m][m];
  #pragma unroll
  for (int m = 0; m <= 6; m++){
    #pragma unroll
    for (int l = m+2; l <= 6; l++)
      P[l][m] = ((2.f*l - 1.f)*ct*P[l-1][m] - (float)(l+m-1)*P[l-2][m]) / (float)(l-m);
  }
  float cmv[7], smv[7];
  #pragma unroll
  for (int m = 0; m <= 6; m++){ cmv[m] = cosf((float)m*phi); smv[m] = sinf((float)m*phi); }
  const double FOURPI = 12.566370614359172;
  int k = 0;
  #pragma unroll
  for (int l = 0; l <= 6; l++){
    #pragma unroll
    for (int mm = -l; mm <= l; mm++){
      int am = mm < 0 ? -mm : mm;
      double ratio = 1.0;
      for (int i = l-am+1; i <= l+am; i++) ratio /= (double)i;
      double nrm = sqrt((2.0*l + 1.0)/FOURPI*ratio);
      float v;
      if (mm == 0)      v = (float)nrm * P[l][0];
      else if (mm > 0)  v = (float)(1.4142135623730951*nrm) * P[l][am] * cmv[am];
      else              v = (float)(1.4142135623730951*nrm) * P[l][am] * smv[am];
      Y[(size_t)e*49 + k] = v; k++;
    }
  }
}

// ------------- layer-1 of radial MLPs: windowed gaussian @ W + b, silu -------------
// exp(-1794*(d-off)^2) underflows f32 beyond ~26 taps -> 64-tap window is exact.
__global__ __launch_bounds__(128) void k_rad1(const float* __restrict__ dv, const float* __restrict__ Wm,
                                              const float* __restrict__ bias, float* __restrict__ out){
  int e = blockIdx.x;
  int j = threadIdx.x;
  float d = dv[e];
  const float STEPF = (float)(5.0/599.0);
  const double step_d = (double)STEPF;
  const float GC = (float)(-0.5/((2.0*step_d)*(2.0*step_d)));
  __shared__ float g[64];
  int bc = (int)rintf(d / STEPF);
  int b0 = bc - 32;
  if (j < 64){
    int b = b0 + j;
    float gg = 0.f;
    if (b >= 0 && b < 600){
      float off = (float)((double)b * (5.0/599.0));
      float t = d - off;
      gg = expf(GC*t*t);
    }
    g[j] = gg;
  }
  __syncthreads();
  float acc = bias ? bias[j] : 0.f;
  #pragma unroll 8
  for (int i = 0; i < 64; i++){
    int b = b0 + i;
    if (b >= 0 && b < 600) acc += g[i]*Wm[b*CD + j];
  }
  out[(size_t)e*CD + j] = siluf(acc);
}

// ---------------- tiled f32 GEMM: C = act(A@B + bias), optional += ----------------
template<int ACT, int ACCUM>
__global__ __launch_bounds__(256) void k_gemm(const float* __restrict__ A, const float* __restrict__ B,
                                              const float* __restrict__ bias, float* __restrict__ C,
                                              int M, int Nc, int K){
  __shared__ float As[64][17];
  __shared__ float Bs[16][64];
  int bm = blockIdx.y*64, bn = blockIdx.x*64;
  int tid = threadIdx.x;
  int tx = tid & 15, ty = tid >> 4;
  float acc[4][4] = {{0.f,0.f,0.f,0.f},{0.f,0.f,0.f,0.f},{0.f,0.f,0.f,0.f},{0.f,0.f,0.f,0.f}};
  for (int k0 = 0; k0 < K; k0 += 16){
    #pragma unroll
    for (int i = tid; i < 1024; i += 256){
      int m = i >> 4, kk = i & 15;
      int row = bm + m;
      As[m][kk] = (row < M) ? A[(size_t)row*K + k0 + kk] : 0.f;
    }
    #pragma unroll
    for (int i = tid; i < 1024; i += 256){
      int kk = i >> 6, n = i & 63;
      Bs[kk][n] = B[(size_t)(k0 + kk)*Nc + bn + n];
    }
    __syncthreads();
    #pragma unroll
    for (int kk = 0; kk < 16; kk++){
      float a0 = As[ty*4+0][kk];
      float a1 = As[ty*4+1][kk];
      float a2 = As[ty*4+2][kk];
      float a3 = As[ty*4+3][kk];
      float4 b4 = *(const float4*)&Bs[kk][tx*4];
      acc[0][0]+=a0*b4.x; acc[0][1]+=a0*b4.y; acc[0][2]+=a0*b4.z; acc[0][3]+=a0*b4.w;
      acc[1][0]+=a1*b4.x; acc[1][1]+=a1*b4.y; acc[1][2]+=a1*b4.z; acc[1][3]+=a1*b4.w;
      acc[2][0]+=a2*b4.x; acc[2][1]+=a2*b4.y; acc[2][2]+=a2*b4.z; acc[2][3]+=a2*b4.w;
      acc[3][0]+=a3*b4.x; acc[3][1]+=a3*b4.y; acc[3][2]+=a3*b4.z; acc[3][3]+=a3*b4.w;
    }
    __syncthreads();
  }
  #pragma unroll
  for (int i = 0; i < 4; i++){
    int row = bm + ty*4 + i;
    if (row >= M) continue;
    #pragma unroll
    for (int j = 0; j < 4; j++){
      int col = bn + tx*4 + j;
      float v = acc[i][j];
      if (bias) v += bias[col];
      if (ACT == 1) v = siluf(v);
      size_t idx = (size_t)row*Nc + col;
      if (ACCUM) C[idx] += v; else C[idx] = v;
    }
  }
}

// ---------------- node init: embedding + Y (x) rad_deg scatter via CSR ----------------
__global__ __launch_bounds__(128) void k_init(const float* __restrict__ pos, const float* __restrict__ table,
                                              const float* __restrict__ Yb, const float* __restrict__ radd,
                                              const int* __restrict__ rowptr, const int* __restrict__ eid,
                                              float* __restrict__ x){
  int n = blockIdx.x;
  int c = threadIdx.x;
  const float DLO = -3.26267f;
  const float DRG = (float)(3.295396 - (-3.26267));
  float p0 = pos[n*3+0], p1 = pos[n*3+1], p2 = pos[n*3+2];
  int t0 = min(127, max(0, (int)rintf((p0 - DLO)/DRG*128.f - 0.5f)));
  int t1 = min(127, max(0, (int)rintf((p1 - DLO)/DRG*128.f - 0.5f)));
  int t2 = min(127, max(0, (int)rintf((p2 - DLO)/DRG*128.f - 0.5f)));
  float emb = table[t0*CD + c] + table[t1*CD + c] + table[t2*CD + c];
  __shared__ float Yl[49];
  __shared__ float rl[896];
  float acc[NCO];
  #pragma unroll
  for (int k = 0; k < NCO; k++) acc[k] = 0.f;
  int pA = rowptr[n], pB = rowptr[n+1];
  for (int p = pA; p < pB; p++){
    int e = eid[p];
    if (c < 49) Yl[c] = Yb[(size_t)e*49 + c];
    #pragma unroll
    for (int q = 0; q < 7; q++) rl[q*128 + c] = radd[(size_t)e*896 + q*128 + c];
    __syncthreads();
    #pragma unroll
    for (int k = 0; k < NCO; k++){
      acc[k] += Yl[k]*rl[deg_of(k)*128 + c];
    }
    __syncthreads();
  }
  size_t base = (size_t)n*NCO*CD;
  x[base + c] = emb + acc[0]*(1.f/3.f);
  #pragma unroll
  for (int k = 1; k < NCO; k++) x[base + k*CD + c] = acc[k]*(1.f/3.f);
}

// ---------------- degree-grouped RMS norm ----------------
__global__ __launch_bounds__(128) void k_rmsnorm(const float* __restrict__ x, const float* __restrict__ w,
                                                 float* __restrict__ out){
  int n = blockIdx.x;
  int c = threadIdx.x;
  const float* xb = x + (size_t)n*NCO*CD;
  float vals[NCO];
  float ss[7] = {0,0,0,0,0,0,0};
  #pragma unroll
  for (int k = 0; k < NCO; k++){
    float v = xb[k*CD + c];
    vals[k] = v;
    ss[deg_of(k)] += v*v;
  }
  __shared__ float red[7][128];
  #pragma unroll
  for (int l = 0; l < 7; l++) red[l][c] = ss[l];
  __syncthreads();
  __shared__ float inv[7];
  if (c < 7){
    float s = 0.f;
    for (int i = 0; i < 128; i++) s += red[c][i];
    float ms = s / ((float)(2*c + 1)*128.f);
    inv[c] = 1.f / sqrtf(ms + 1e-6f);
  }
  __syncthreads();
  size_t base = (size_t)n*NCO*CD;
  #pragma unroll
  for (int k = 0; k < NCO; k++){
    int l = deg_of(k);
    out[base + k*CD + c] = vals[k]*inv[l]*w[l*CD + c];
  }
}

// ---------------- gather restricted rows / scatter-add back ----------------
__global__ void k_gather(const float* __restrict__ h, float* __restrict__ hr){
  int i = blockIdx.x*blockDim.x + threadIdx.x;
  if (i >= NN*NRr*CD) return;
  int c = i & 127;
  int kr = (i >> 7) % 29;
  int n = i / (29*128);
  hr[i] = h[((size_t)n*49 + c_res[kr])*128 + c];
}
__global__ void k_scatadd(const float* __restrict__ orr, float* __restrict__ x){
  int i = blockIdx.x*blockDim.x + threadIdx.x;
  if (i >= NN*NRr*CD) return;
  int c = i & 127;
  int kr = (i >> 7) % 29;
  int n = i / (29*128);
  x[((size_t)n*49 + c_res[kr])*128 + c] += orr[i];
}

// ---------------- attention small kernels ----------------
__global__ void k_logits(const float* __restrict__ XS, const float* __restrict__ XT,
                         const float* __restrict__ rad, const float* __restrict__ avec,
                         const int* __restrict__ src, const int* __restrict__ dst,
                         float* __restrict__ lg){
  int idx = blockIdx.x*blockDim.x + threadIdx.x;
  if (idx >= NE*8) return;
  int e = idx >> 3, hh = idx & 7;
  int s = src[e], t = dst[e];
  float acc = 0.f;
  #pragma unroll
  for (int dd = 0; dd < 16; dd++){
    int j = hh*16 + dd;
    float m = (XS[(size_t)s*NRr*CD + j] + XT[(size_t)t*NRr*CD + j]) * rad[(size_t)e*CD + j];
    acc += siluf(m)*avec[hh*16 + dd];
  }
  lg[idx] = acc;
}
__global__ void k_softmax(const float* __restrict__ lg, const int* __restrict__ rowptr,
                          const int* __restrict__ eid, float* __restrict__ mx, float* __restrict__ den){
  int idx = blockIdx.x*blockDim.x + threadIdx.x;
  if (idx >= NN*8) return;
  int n = idx >> 3, hh = idx & 7;
  int p0 = rowptr[n], p1 = rowptr[n+1];
  float m = -1e30f;
  for (int p = p0; p < p1; p++) m = fmaxf(m, lg[eid[p]*8 + hh]);
  float s = 0.f;
  for (int p = p0; p < p1; p++) s += expf(lg[eid[p]*8 + hh] - m);
  mx[idx] = m; den[idx] = s;
}
__global__ void k_alpha(const float* __restrict__ lg, const float* __restrict__ mx,
                        const float* __restrict__ den, const int* __restrict__ dst,
                        float* __restrict__ al){
  int idx = blockIdx.x*blockDim.x + threadIdx.x;
  if (idx >= NE*8) return;
  int e = idx >> 3, hh = idx & 7;
  int t = dst[e];
  al[idx] = expf(lg[idx] - mx[t*8 + hh]) / fmaxf(den[t*8 + hh], 1e-9f);
}
__global__ __launch_bounds__(128) void k_msg(const float* __restrict__ XS, const float* __restrict__ XT,
                                             const float* __restrict__ rad, const int* __restrict__ src,
                                             const int* __restrict__ dst, int e0, float* __restrict__ msgR){
  int e = e0 + blockIdx.x;
  int k = blockIdx.y;
  int c = threadIdx.x;
  int s = src[e], t = dst[e];
  float v = (XS[((size_t)s*NRr + k)*CD + c] + XT[((size_t)t*NRr + k)*CD + c]) * rad[(size_t)e*CD + c];
  msgR[((size_t)(e - e0)*NRr + k)*CD + c] = v;
}
__global__ __launch_bounds__(128) void k_agg(const float* __restrict__ V, const float* __restrict__ al,
                                             const int* __restrict__ rowptr, const int* __restrict__ eid,
                                             int e0, int e1, int first, float* __restrict__ agg){
  int n = blockIdx.x;
  int k = blockIdx.y;
  int c = threadIdx.x;
  size_t oidx = ((size_t)n*NRr + k)*CD + c;
  float s = first ? 0.f : agg[oidx];
  int hh = c >> 4;
  int p0 = rowptr[n], p1 = rowptr[n+1];
  for (int p = p0; p < p1; p++){
    int e = eid[p];
    if (e < e0 || e >= e1) continue;
    s += al[e*8 + hh]*V[((size_t)(e - e0)*NRr + k)*CD + c];
  }
  agg[oidx] = s;
}

// ---------------- FFN gating (per node chunk) ----------------
__global__ void k_gate(float* __restrict__ f1, int nnodes){
  int i = blockIdx.x*blockDim.x + threadIdx.x;
  if (i >= nnodes*512) return;
  int n = i >> 9, f = i & 511;
  size_t base = (size_t)n*49*512 + f;
  float s = f1[base];
  float sg = 1.f/(1.f + expf(-s));
  f1[base] = s*sg;
  for (int k = 1; k < 49; k++){
    size_t id = base + (size_t)k*512;
    f1[id] = f1[id]*sg;
  }
}

// ---------------- pooling ----------------
__global__ void k_pool(const float* __restrict__ orr, const int* __restrict__ gs, float* __restrict__ out){
  int i = blockIdx.x*blockDim.x + threadIdx.x;
  if (i >= NG*NCO*CD) return;
  int c = i & 127;
  int k = (i >> 7) % 49;
  int g = i / (49*128);
  int kr = c_rinv[k];
  float v = 0.f;
  if (kr >= 0){
    int a = gs[g], b = gs[g+1];
    float s = 0.f;
    for (int n = a; n < b; n++) s += orr[((size_t)n*29 + kr)*128 + c];
    int cnt = b - a;
    v = s / (float)(cnt > 0 ? cnt : 1);
  }
  out[i] = v;
}

extern "C" void kernel_launch(void* const* d_in, const int* in_sizes, int n_in,
                              void* d_out, int out_size, void* d_ws, size_t ws_size,
                              hipStream_t stream){
  const float* pos    = (const float*)d_in[0];
  const float* evec   = (const float*)d_in[1];
  const int*   eidx   = (const int*)  d_in[2];
  const int*   batch  = (const int*)  d_in[3];
  const float* table  = (const float*)d_in[4];
  const float* deg_w1 = (const float*)d_in[5];
  const float* deg_b1 = (const float*)d_in[6];
  const float* deg_w2 = (const float*)d_in[7];
  const float* deg_b2 = (const float*)d_in[8];
  const float* deg_w3 = (const float*)d_in[9];
  const float* attn_nw= (const float*)d_in[10];
  const float* w_src  = (const float*)d_in[11];
  const float* w_tgt  = (const float*)d_in[12];
  const float* rad_w1 = (const float*)d_in[13];
  const float* rad_b1 = (const float*)d_in[14];
  const float* rad_w2 = (const float*)d_in[15];
  const float* avec   = (const float*)d_in[16];
  const float* w_val  = (const float*)d_in[17];
  const float* w_proj = (const float*)d_in[18];
  const float* ffn_nw = (const float*)d_in[19];
  const float* ffn_w1 = (const float*)d_in[20];
  const float* ffn_w2 = (const float*)d_in[21];
  const float* fin_nw = (const float*)d_in[22];
  const float* lw_src = (const float*)d_in[23];
  const float* lw_tgt = (const float*)d_in[24];
  const float* lrad_w1= (const float*)d_in[25];
  const float* lrad_b1= (const float*)d_in[26];
  const float* lrad_w2= (const float*)d_in[27];
  const float* lavec  = (const float*)d_in[28];
  const float* lw_val = (const float*)d_in[29];
  const float* lw_proj= (const float*)d_in[30];

  const int* srcp = eidx;
  const int* dstp = eidx + NE;

  float* W = (float*)d_ws;
  size_t o = 0;
  float* X   = W + o; o += (size_t)NN*49*128;   // 12,845,056
  float* Hb  = W + o; o += (size_t)NN*49*128;   // 12,845,056 (also msg/V chunks, proj out)
  float* HR  = W + o; o += (size_t)NN*29*128;   // 7,602,176  (also agg)
  float* XSb = W + o; o += (size_t)NN*29*128;   // 7,602,176  (also rad_deg part 1, ffn f1 chunk part 1)
  float* XTb = W + o; o += (size_t)NN*29*128;   // 7,602,176  (spill region for rad_deg / f1 chunk)
  float* R1  = W + o; o += (size_t)NE*128;
  float* R2  = W + o; o += (size_t)NE*128;
  float* Yb  = W + o; o += (size_t)NE*49;
  float* DV  = W + o; o += (size_t)NE;
  float* LG  = W + o; o += (size_t)NE*8;
  float* AL  = W + o; o += (size_t)NE*8;
  float* MX  = W + o; o += (size_t)NN*8;
  float* DEN = W + o; o += (size_t)NN*8;
  int* CNT = (int*)(W + o); o += NN;
  int* RP  = (int*)(W + o); o += NN + 1;
  int* EID = (int*)(W + o); o += NE;
  int* GS  = (int*)(W + o); o += NG + 1;
  (void)DEN; (void)ws_size; (void)in_sizes; (void)n_in; (void)out_size;

  // aliases (lifetimes disjoint from their hosts' primary use):
  float* RADD = XSb;                              // E*896 = 11.0M <= XSb+XTb (15.2M)
  float* F1CH = XSb;                              // FCHUNK*49*512 = 12.85M <= XSb+XTb (15.2M)
  float* MSG  = Hb;                               // ECHUNK*29*128 = 5.70M
  float* VCH  = Hb + (size_t)ECHUNK*29*128;       // 5.70M  (MSG+VCH = 11.4M <= Hb 12.8M)
  float* AG   = HR;
  float* OR_  = Hb;

  // CSR + groups (parallel, deterministic)
  k_hist<<<1, 1024, 0, stream>>>(dstp, CNT);
  k_scan2<<<1, 1024, 0, stream>>>(CNT, RP);
  k_fillw<<<NN/4, 256, 0, stream>>>(dstp, RP, EID);
  k_gstart<<<1, 32, 0, stream>>>(batch, GS);

  // geometry
  k_geom<<<48, 256, 0, stream>>>(evec, Yb, DV);

  // degree embedding MLP: 600->128 (silu) -> 128 (silu) -> 896
  k_rad1<<<NE, 128, 0, stream>>>(DV, deg_w1, deg_b1, R1);
  k_gemm<1,0><<<dim3(2, NE/64), 256, 0, stream>>>(R1, deg_w2, deg_b2, R2, NE, 128, 128);
  k_gemm<0,0><<<dim3(14, NE/64), 256, 0, stream>>>(R2, deg_w3, nullptr, RADD, NE, 896, 128);
  k_init<<<NN, 128, 0, stream>>>(pos, table, Yb, RADD, RP, EID, X);

  for (int i = 0; i < 3; i++){
    const float* nw  = (i < 2) ? attn_nw + (size_t)i*896   : fin_nw;
    const float* ws_ = (i < 2) ? w_src  + (size_t)i*16384 : lw_src;
    const float* wt_ = (i < 2) ? w_tgt  + (size_t)i*16384 : lw_tgt;
    const float* rw1 = (i < 2) ? rad_w1 + (size_t)i*76800 : lrad_w1;
    const float* rb1 = (i < 2) ? rad_b1 + (size_t)i*128   : lrad_b1;
    const float* rw2 = (i < 2) ? rad_w2 + (size_t)i*16384 : lrad_w2;
    const float* av  = (i < 2) ? avec   + (size_t)i*128   : lavec;
    const float* wv  = (i < 2) ? w_val  + (size_t)i*16384 : lw_val;
    const float* wp  = (i < 2) ? w_proj + (size_t)i*16384 : lw_proj;

    k_rmsnorm<<<NN, 128, 0, stream>>>(X, nw, Hb);
    k_gather<<<(NN*NRr*CD + 255)/256, 256, 0, stream>>>(Hb, HR);
    k_gemm<0,0><<<dim3(2, NN*NRr/64), 256, 0, stream>>>(HR, ws_, nullptr, XSb, NN*NRr, 128, 128);
    k_gemm<0,0><<<dim3(2, NN*NRr/64), 256, 0, stream>>>(HR, wt_, nullptr, XTb, NN*NRr, 128, 128);
    k_rad1<<<NE, 128, 0, stream>>>(DV, rw1, rb1, R1);
    k_gemm<0,0><<<dim3(2, NE/64), 256, 0, stream>>>(R1, rw2, nullptr, R2, NE, 128, 128);
    k_logits<<<(NE*8 + 255)/256, 256, 0, stream>>>(XSb, XTb, R2, av, srcp, dstp, LG);
    k_softmax<<<(NN*8 + 255)/256, 256, 0, stream>>>(LG, RP, EID, MX, DEN);
    k_alpha<<<(NE*8 + 255)/256, 256, 0, stream>>>(LG, MX, DEN, dstp, AL);
    for (int ch = 0; ch < NE/ECHUNK; ch++){
      int e0 = ch*ECHUNK;
      k_msg<<<dim3(ECHUNK, NRr), 128, 0, stream>>>(XSb, XTb, R2, srcp, dstp, e0, MSG);
      k_gemm<0,0><<<dim3(2, ECHUNK*NRr/64), 256, 0, stream>>>(MSG, wv, nullptr, VCH, ECHUNK*NRr, 128, 128);
      k_agg<<<dim3(NN, NRr), 128, 0, stream>>>(VCH, AL, RP, EID, e0, e0 + ECHUNK, ch == 0, AG);
    }
    k_gemm<0,0><<<dim3(2, NN*NRr/64), 256, 0, stream>>>(AG, wp, nullptr, OR_, NN*NRr, 128, 128);
    if (i < 2){
      k_scatadd<<<(NN*NRr*CD + 255)/256, 256, 0, stream>>>(OR_, X);
      // FFN (chunked over nodes so hidden fits in XSb+XTb)
      k_rmsnorm<<<NN, 128, 0, stream>>>(X, ffn_nw + (size_t)i*896, Hb);
      for (int n0 = 0; n0 < NN; n0 += FCHUNK){
        const float* hA = Hb + (size_t)n0*NCO*CD;
        float* xC = X + (size_t)n0*NCO*CD;
        k_gemm<0,0><<<dim3(8, FCHUNK*NCO/64), 256, 0, stream>>>(hA, ffn_w1 + (size_t)i*65536, nullptr, F1CH, FCHUNK*NCO, 512, 128);
        k_gate<<<(FCHUNK*512 + 255)/256, 256, 0, stream>>>(F1CH, FCHUNK);
        k_gemm<0,1><<<dim3(2, FCHUNK*NCO/64), 256, 0, stream>>>(F1CH, ffn_w2 + (size_t)i*65536, nullptr, xC, FCHUNK*NCO, 128, 512);
      }
    } else {
      k_pool<<<(NG*NCO*CD + 255)/256, 256, 0, stream>>>(OR_, GS, (float*)d_out);
    }
  }
}

// Round 5
// 2006.462 us; speedup vs baseline: 2.5417x; 2.1534x over previous
//
#include <hip/hip_runtime.h>
#include <math.h>

#define NN 2048
#define NE 12288
#define NCO 49
#define NRr 29
#define CD 128
#define NG 16
#define ECHUNK 3072
#define FCHUNK 512   // nodes per FFN chunk

typedef unsigned short u16;
typedef short bhalf8 __attribute__((ext_vector_type(8)));
typedef float fvec4 __attribute__((ext_vector_type(4)));

// RESTRICT: indices k (0..48) with |m|<=2.
__constant__ int c_res[29] = {0,1,2,3,4,5,6,7,8,10,11,12,13,14,18,19,20,21,22,28,29,30,31,32,40,41,42,43,44};
__constant__ int c_rinv[49] = {0,1,2,3,4,5,6,7,8,-1,9,10,11,12,13,-1,-1,-1,14,15,16,17,18,-1,-1,-1,-1,-1,19,20,21,22,23,-1,-1,-1,-1,-1,-1,-1,24,25,26,27,28,-1,-1,-1,-1};

__device__ __forceinline__ constexpr int deg_of(int k){
  return (k<1)?0:(k<4)?1:(k<9)?2:(k<16)?3:(k<25)?4:(k<36)?5:6;
}
__device__ __forceinline__ float siluf(float x){ return x / (1.f + expf(-x)); }
__device__ __forceinline__ u16 f2bf(float f){
  unsigned int u = __float_as_uint(f);
  unsigned int r = (u + 0x7FFFu + ((u >> 16) & 1u)) >> 16;
  return (u16)r;
}
__device__ __forceinline__ unsigned int pk(u16 lo, u16 hi){ return (unsigned int)lo | ((unsigned int)hi << 16); }

// ---------------- CSR build (deterministic, parallel) ----------------
__global__ __launch_bounds__(1024) void k_hist(const int* __restrict__ dst, int* __restrict__ cnt){
  __shared__ int h[NN];
  for (int i = threadIdx.x; i < NN; i += 1024) h[i] = 0;
  __syncthreads();
  for (int e = threadIdx.x; e < NE; e += 1024) atomicAdd(&h[dst[e]], 1);
  __syncthreads();
  for (int i = threadIdx.x; i < NN; i += 1024) cnt[i] = h[i];
}
__global__ __launch_bounds__(1024) void k_scan2(const int* __restrict__ cnt, int* __restrict__ rowptr){
  __shared__ int a[NN], b[NN];
  int t = threadIdx.x;
  for (int i = t; i < NN; i += 1024) a[i] = cnt[i];
  __syncthreads();
  int* pin = a; int* pout = b;
  for (int off = 1; off < NN; off <<= 1){
    for (int i = t; i < NN; i += 1024)
      pout[i] = pin[i] + ((i >= off) ? pin[i - off] : 0);
    __syncthreads();
    int* tmp = pin; pin = pout; pout = tmp;
  }
  for (int i = t; i < NN; i += 1024) rowptr[i + 1] = pin[i];
  if (t == 0) rowptr[0] = 0;
}
__global__ __launch_bounds__(256) void k_fillw(const int* __restrict__ dst, const int* __restrict__ rowptr,
                                               int* __restrict__ eid){
  int wave = threadIdx.x >> 6;
  int lane = threadIdx.x & 63;
  int n = blockIdx.x*4 + wave;
  if (n >= NN) return;
  int base = rowptr[n];
  for (int e0 = 0; e0 < NE; e0 += 64){
    int e = e0 + lane;
    bool m = (dst[e] == n);
    unsigned long long mask = __ballot(m);
    if (m){
      int pos = base + __popcll(mask & ((1ull << lane) - 1ull));
      eid[pos] = e;
    }
    base += __popcll(mask);
  }
}
__global__ void k_gstart(const int* __restrict__ batch, int* __restrict__ gs){
  int g = threadIdx.x;
  if (g > NG) return;
  int s = 0;
  for (int n = 0; n < NN; n++) s += (batch[n] < g);
  gs[g] = s;
}

// ---------------- weight cast+transpose: [K][N] f32 -> [N][K] bf16 ----------------
__global__ void k_cast(const float* __restrict__ in, u16* __restrict__ out, int K, int N){
  int i = blockIdx.x*blockDim.x + threadIdx.x;
  if (i >= K*N) return;
  int n = i / K, k = i - n*K;
  out[i] = f2bf(in[(size_t)k*N + n]);
}

// ---------------- geometry ----------------
__global__ void k_geom(const float* __restrict__ ev, float* __restrict__ Y, float* __restrict__ dv){
  int e = blockIdx.x*blockDim.x + threadIdx.x;
  if (e >= NE) return;
  float x = ev[e*3+0], y = ev[e*3+1], z = ev[e*3+2];
  float r = sqrtf(x*x + y*y + z*z);
  dv[e] = r;
  float rn = fmaxf(r, 1e-8f);
  float ux = x/rn, uy = y/rn, uz = z/rn;
  float ct = fminf(fmaxf(uz, -1.f), 1.f);
  float st = sqrtf(fminf(fmaxf(1.f - ct*ct, 1e-12f), 1.f));
  float phi = atan2f(uy, ux);
  float P[7][7];
  P[0][0] = 1.f;
  #pragma unroll
  for (int m = 1; m <= 6; m++) P[m][m] = -(2.f*m - 1.f)*st*P[m-1][m-1];
  #pragma unroll
  for (int m = 0; m <= 5; m++) P[m+1][m] = (2.f*m + 1.f)*ct*P[m][m];
  #pragma unroll
  for (int m = 0; m <= 6; m++){
    #pragma unroll
    for (int l = m+2; l <= 6; l++)
      P[l][m] = ((2.f*l - 1.f)*ct*P[l-1][m] - (float)(l+m-1)*P[l-2][m]) / (float)(l-m);
  }
  float cmv[7], smv[7];
  #pragma unroll
  for (int m = 0; m <= 6; m++){ cmv[m] = cosf((float)m*phi); smv[m] = sinf((float)m*phi); }
  const double FOURPI = 12.566370614359172;
  int k = 0;
  #pragma unroll
  for (int l = 0; l <= 6; l++){
    #pragma unroll
    for (int mm = -l; mm <= l; mm++){
      int am = mm < 0 ? -mm : mm;
      double ratio = 1.0;
      for (int i = l-am+1; i <= l+am; i++) ratio /= (double)i;
      double nrm = sqrt((2.0*l + 1.0)/FOURPI*ratio);
      float v;
      if (mm == 0)      v = (float)nrm * P[l][0];
      else if (mm > 0)  v = (float)(1.4142135623730951*nrm) * P[l][am] * cmv[am];
      else              v = (float)(1.4142135623730951*nrm) * P[l][am] * smv[am];
      Y[(size_t)e*49 + k] = v; k++;
    }
  }
}

// ------------- layer-1 of radial MLPs (windowed gaussian, exact) -------------
__global__ __launch_bounds__(128) void k_rad1(const float* __restrict__ dv, const float* __restrict__ Wm,
                                              const float* __restrict__ bias, float* __restrict__ out){
  int e = blockIdx.x;
  int j = threadIdx.x;
  float d = dv[e];
  const float STEPF = (float)(5.0/599.0);
  const double step_d = (double)STEPF;
  const float GC = (float)(-0.5/((2.0*step_d)*(2.0*step_d)));
  __shared__ float g[64];
  int bc = (int)rintf(d / STEPF);
  int b0 = bc - 32;
  if (j < 64){
    int b = b0 + j;
    float gg = 0.f;
    if (b >= 0 && b < 600){
      float off = (float)((double)b * (5.0/599.0));
      float t = d - off;
      gg = expf(GC*t*t);
    }
    g[j] = gg;
  }
  __syncthreads();
  float acc = bias ? bias[j] : 0.f;
  #pragma unroll 8
  for (int i = 0; i < 64; i++){
    int b = b0 + i;
    if (b >= 0 && b < 600) acc += g[i]*Wm[b*CD + j];
  }
  out[(size_t)e*CD + j] = siluf(acc);
}

// ---------------- MFMA bf16 GEMM: C = act(A@B^T + bias), optional +=, optional fused msg A ----------------
// A: f32 [M][K] (row-major), Bt: bf16 [N][K] (pre-transposed), C: f32 [M][N].
// M%64==0, N%64==0, K%64==0 assumed.
// FMSG: A row (bm+row) maps to edge e=e0+(row/29), kq=row%29; A[row][c]=(XS[s,kq,c]+XT[t,kq,c])*rad[e,c].
template<int ACT, int ACCUM, int FMSG>
__global__ __launch_bounds__(256) void k_mgemm(
    const float* __restrict__ A, const u16* __restrict__ Bt,
    const float* __restrict__ bias, float* __restrict__ C,
    int M, int N, int K,
    const float* __restrict__ XS, const float* __restrict__ XT,
    const float* __restrict__ rad, const int* __restrict__ src,
    const int* __restrict__ dstp, int e0)
{
  __shared__ __align__(16) u16 Asl[64*64];
  __shared__ __align__(16) u16 Bsl[64*64];
  int tid = threadIdx.x;
  int bm = blockIdx.y*64, bn = blockIdx.x*64;
  int wid = tid >> 6, lane = tid & 63;
  int wr = wid >> 1, wc = wid & 1;
  int lr = lane & 15, lk = lane >> 4;
  fvec4 acc[2][2] = {};
  for (int k0 = 0; k0 < K; k0 += 64){
    #pragma unroll
    for (int h = 0; h < 2; h++){
      int lin = tid + h*256;          // 0..511: 64 rows x 8 k-groups
      int row = lin >> 3, kg = lin & 7;
      float v[8];
      if (FMSG){
        int gr = bm + row;
        int el = gr / 29, kq = gr - el*29;
        int e = e0 + el;
        int s = src[e], t = dstp[e];
        const float* xs = XS + ((size_t)s*29 + kq)*128 + k0 + kg*8;
        const float* xt = XT + ((size_t)t*29 + kq)*128 + k0 + kg*8;
        const float* rd = rad + (size_t)e*128 + k0 + kg*8;
        #pragma unroll
        for (int j = 0; j < 8; j++) v[j] = (xs[j] + xt[j]) * rd[j];
      } else {
        const float* ap = A + (size_t)(bm + row)*K + k0 + kg*8;
        #pragma unroll
        for (int j = 0; j < 8; j++) v[j] = ap[j];
      }
      uint4 q;
      q.x = pk(f2bf(v[0]), f2bf(v[1]));
      q.y = pk(f2bf(v[2]), f2bf(v[3]));
      q.z = pk(f2bf(v[4]), f2bf(v[5]));
      q.w = pk(f2bf(v[6]), f2bf(v[7]));
      *(uint4*)&Asl[row*64 + ((kg*8) ^ ((row & 7)*8))] = q;
      const u16* bp = Bt + (size_t)(bn + row)*K + k0 + kg*8;
      *(uint4*)&Bsl[row*64 + ((kg*8) ^ ((row & 7)*8))] = *(const uint4*)bp;
    }
    __syncthreads();
    #pragma unroll
    for (int ks = 0; ks < 2; ks++){
      bhalf8 af[2], bfr[2];
      int kg = ks*4 + lk;
      #pragma unroll
      for (int mi = 0; mi < 2; mi++){
        int ar = wr*32 + mi*16 + lr;
        af[mi] = *(const bhalf8*)&Asl[ar*64 + ((kg*8) ^ ((ar & 7)*8))];
      }
      #pragma unroll
      for (int ni = 0; ni < 2; ni++){
        int br = wc*32 + ni*16 + lr;
        bfr[ni] = *(const bhalf8*)&Bsl[br*64 + ((kg*8) ^ ((br & 7)*8))];
      }
      #pragma unroll
      for (int mi = 0; mi < 2; mi++)
        #pragma unroll
        for (int ni = 0; ni < 2; ni++)
          acc[mi][ni] = __builtin_amdgcn_mfma_f32_16x16x32_bf16(af[mi], bfr[ni], acc[mi][ni], 0, 0, 0);
    }
    __syncthreads();
  }
  #pragma unroll
  for (int mi = 0; mi < 2; mi++){
    #pragma unroll
    for (int ni = 0; ni < 2; ni++){
      #pragma unroll
      for (int j = 0; j < 4; j++){
        int row = bm + wr*32 + mi*16 + lk*4 + j;
        int col = bn + wc*32 + ni*16 + lr;
        float v = acc[mi][ni][j];
        if (bias) v += bias[col];
        if (ACT == 1) v = siluf(v);
        size_t idx = (size_t)row*N + col;
        if (ACCUM) C[idx] += v; else C[idx] = v;
      }
    }
  }
}

// ---------------- node init ----------------
__global__ __launch_bounds__(128) void k_init(const float* __restrict__ pos, const float* __restrict__ table,
                                              const float* __restrict__ Yb, const float* __restrict__ radd,
                                              const int* __restrict__ rowptr, const int* __restrict__ eid,
                                              float* __restrict__ x){
  int n = blockIdx.x;
  int c = threadIdx.x;
  const float DLO = -3.26267f;
  const float DRG = (float)(3.295396 - (-3.26267));
  float p0 = pos[n*3+0], p1 = pos[n*3+1], p2 = pos[n*3+2];
  int t0 = min(127, max(0, (int)rintf((p0 - DLO)/DRG*128.f - 0.5f)));
  int t1 = min(127, max(0, (int)rintf((p1 - DLO)/DRG*128.f - 0.5f)));
  int t2 = min(127, max(0, (int)rintf((p2 - DLO)/DRG*128.f - 0.5f)));
  float emb = table[t0*CD + c] + table[t1*CD + c] + table[t2*CD + c];
  __shared__ float Yl[49];
  __shared__ float rl[896];
  float acc[NCO];
  #pragma unroll
  for (int k = 0; k < NCO; k++) acc[k] = 0.f;
  int pA = rowptr[n], pB = rowptr[n+1];
  for (int p = pA; p < pB; p++){
    int e = eid[p];
    if (c < 49) Yl[c] = Yb[(size_t)e*49 + c];
    #pragma unroll
    for (int q = 0; q < 7; q++) rl[q*128 + c] = radd[(size_t)e*896 + q*128 + c];
    __syncthreads();
    #pragma unroll
    for (int k = 0; k < NCO; k++){
      acc[k] += Yl[k]*rl[deg_of(k)*128 + c];
    }
    __syncthreads();
  }
  size_t base = (size_t)n*NCO*CD;
  x[base + c] = emb + acc[0]*(1.f/3.f);
  #pragma unroll
  for (int k = 1; k < NCO; k++) x[base + k*CD + c] = acc[k]*(1.f/3.f);
}

// ---------------- degree-grouped RMS norm ----------------
__global__ __launch_bounds__(128) void k_rmsnorm(const float* __restrict__ x, const float* __restrict__ w,
                                                 float* __restrict__ out){
  int n = blockIdx.x;
  int c = threadIdx.x;
  const float* xb = x + (size_t)n*NCO*CD;
  float vals[NCO];
  float ss[7] = {0,0,0,0,0,0,0};
  #pragma unroll
  for (int k = 0; k < NCO; k++){
    float v = xb[k*CD + c];
    vals[k] = v;
    ss[deg_of(k)] += v*v;
  }
  __shared__ float red[7][128];
  #pragma unroll
  for (int l = 0; l < 7; l++) red[l][c] = ss[l];
  __syncthreads();
  __shared__ float inv[7];
  if (c < 7){
    float s = 0.f;
    for (int i = 0; i < 128; i++) s += red[c][i];
    float ms = s / ((float)(2*c + 1)*128.f);
    inv[c] = 1.f / sqrtf(ms + 1e-6f);
  }
  __syncthreads();
  size_t base = (size_t)n*NCO*CD;
  #pragma unroll
  for (int k = 0; k < NCO; k++){
    int l = deg_of(k);
    out[base + k*CD + c] = vals[k]*inv[l]*w[l*CD + c];
  }
}

// ---------------- gather restricted rows / scatter-add back ----------------
__global__ void k_gather(const float* __restrict__ h, float* __restrict__ hr){
  int i = blockIdx.x*blockDim.x + threadIdx.x;
  if (i >= NN*NRr*CD) return;
  int c = i & 127;
  int kr = (i >> 7) % 29;
  int n = i / (29*128);
  hr[i] = h[((size_t)n*49 + c_res[kr])*128 + c];
}
__global__ void k_scatadd(const float* __restrict__ orr, float* __restrict__ x){
  int i = blockIdx.x*blockDim.x + threadIdx.x;
  if (i >= NN*NRr*CD) return;
  int c = i & 127;
  int kr = (i >> 7) % 29;
  int n = i / (29*128);
  x[((size_t)n*49 + c_res[kr])*128 + c] += orr[i];
}

// ---------------- attention small kernels ----------------
__global__ void k_logits(const float* __restrict__ XS, const float* __restrict__ XT,
                         const float* __restrict__ rad, const float* __restrict__ avec,
                         const int* __restrict__ src, const int* __restrict__ dst,
                         float* __restrict__ lg){
  int idx = blockIdx.x*blockDim.x + threadIdx.x;
  if (idx >= NE*8) return;
  int e = idx >> 3, hh = idx & 7;
  int s = src[e], t = dst[e];
  float acc = 0.f;
  #pragma unroll
  for (int dd = 0; dd < 16; dd++){
    int j = hh*16 + dd;
    float m = (XS[(size_t)s*NRr*CD + j] + XT[(size_t)t*NRr*CD + j]) * rad[(size_t)e*CD + j];
    acc += siluf(m)*avec[hh*16 + dd];
  }
  lg[idx] = acc;
}
__global__ void k_softmax(const float* __restrict__ lg, const int* __restrict__ rowptr,
                          const int* __restrict__ eid, float* __restrict__ mx, float* __restrict__ den){
  int idx = blockIdx.x*blockDim.x + threadIdx.x;
  if (idx >= NN*8) return;
  int n = idx >> 3, hh = idx & 7;
  int p0 = rowptr[n], p1 = rowptr[n+1];
  float m = -1e30f;
  for (int p = p0; p < p1; p++) m = fmaxf(m, lg[eid[p]*8 + hh]);
  float s = 0.f;
  for (int p = p0; p < p1; p++) s += expf(lg[eid[p]*8 + hh] - m);
  mx[idx] = m; den[idx] = s;
}
__global__ void k_alpha(const float* __restrict__ lg, const float* __restrict__ mx,
                        const float* __restrict__ den, const int* __restrict__ dst,
                        float* __restrict__ al){
  int idx = blockIdx.x*blockDim.x + threadIdx.x;
  if (idx >= NE*8) return;
  int e = idx >> 3, hh = idx & 7;
  int t = dst[e];
  al[idx] = expf(lg[idx] - mx[t*8 + hh]) / fmaxf(den[t*8 + hh], 1e-9f);
}
__global__ __launch_bounds__(128) void k_agg(const float* __restrict__ V, const float* __restrict__ al,
                                             const int* __restrict__ rowptr, const int* __restrict__ eid,
                                             int e0, int e1, int first, float* __restrict__ agg){
  int n = blockIdx.x;
  int k = blockIdx.y;
  int c = threadIdx.x;
  size_t oidx = ((size_t)n*NRr + k)*CD + c;
  float s = first ? 0.f : agg[oidx];
  int hh = c >> 4;
  int p0 = rowptr[n], p1 = rowptr[n+1];
  for (int p = p0; p < p1; p++){
    int e = eid[p];
    if (e < e0 || e >= e1) continue;
    s += al[e*8 + hh]*V[((size_t)(e - e0)*NRr + k)*CD + c];
  }
  agg[oidx] = s;
}

// ---------------- FFN gating (per node chunk) ----------------
__global__ void k_gate(float* __restrict__ f1, int nnodes){
  int i = blockIdx.x*blockDim.x + threadIdx.x;
  if (i >= nnodes*512) return;
  int n = i >> 9, f = i & 511;
  size_t base = (size_t)n*49*512 + f;
  float s = f1[base];
  float sg = 1.f/(1.f + expf(-s));
  f1[base] = s*sg;
  for (int k = 1; k < 49; k++){
    size_t id = base + (size_t)k*512;
    f1[id] = f1[id]*sg;
  }
}

// ---------------- pooling ----------------
__global__ void k_pool(const float* __restrict__ orr, const int* __restrict__ gs, float* __restrict__ out){
  int i = blockIdx.x*blockDim.x + threadIdx.x;
  if (i >= NG*NCO*CD) return;
  int c = i & 127;
  int k = (i >> 7) % 49;
  int g = i / (49*128);
  int kr = c_rinv[k];
  float v = 0.f;
  if (kr >= 0){
    int a = gs[g], b = gs[g+1];
    float s = 0.f;
    for (int n = a; n < b; n++) s += orr[((size_t)n*29 + kr)*128 + c];
    int cnt = b - a;
    v = s / (float)(cnt > 0 ? cnt : 1);
  }
  out[i] = v;
}

extern "C" void kernel_launch(void* const* d_in, const int* in_sizes, int n_in,
                              void* d_out, int out_size, void* d_ws, size_t ws_size,
                              hipStream_t stream){
  const float* pos    = (const float*)d_in[0];
  const float* evec   = (const float*)d_in[1];
  const int*   eidx   = (const int*)  d_in[2];
  const int*   batch  = (const int*)  d_in[3];
  const float* table  = (const float*)d_in[4];
  const float* deg_w1 = (const float*)d_in[5];
  const float* deg_b1 = (const float*)d_in[6];
  const float* deg_w2 = (const float*)d_in[7];
  const float* deg_b2 = (const float*)d_in[8];
  const float* deg_w3 = (const float*)d_in[9];
  const float* attn_nw= (const float*)d_in[10];
  const float* w_src  = (const float*)d_in[11];
  const float* w_tgt  = (const float*)d_in[12];
  const float* rad_w1 = (const float*)d_in[13];
  const float* rad_b1 = (const float*)d_in[14];
  const float* rad_w2 = (const float*)d_in[15];
  const float* avec   = (const float*)d_in[16];
  const float* w_val  = (const float*)d_in[17];
  const float* w_proj = (const float*)d_in[18];
  const float* ffn_nw = (const float*)d_in[19];
  const float* ffn_w1 = (const float*)d_in[20];
  const float* ffn_w2 = (const float*)d_in[21];
  const float* fin_nw = (const float*)d_in[22];
  const float* lw_src = (const float*)d_in[23];
  const float* lw_tgt = (const float*)d_in[24];
  const float* lrad_w1= (const float*)d_in[25];
  const float* lrad_b1= (const float*)d_in[26];
  const float* lrad_w2= (const float*)d_in[27];
  const float* lavec  = (const float*)d_in[28];
  const float* lw_val = (const float*)d_in[29];
  const float* lw_proj= (const float*)d_in[30];

  const int* srcp = eidx;
  const int* dstp = eidx + NE;

  float* W = (float*)d_ws;
  size_t o = 0;
  float* X   = W + o; o += (size_t)NN*49*128;
  float* Hb  = W + o; o += (size_t)NN*49*128;   // also V chunks, proj out
  float* HR  = W + o; o += (size_t)NN*29*128;   // also agg
  float* XSb = W + o; o += (size_t)NN*29*128;   // also rad_deg part, ffn f1 chunk part
  float* XTb = W + o; o += (size_t)NN*29*128;   // spill region
  float* R1  = W + o; o += (size_t)NE*128;
  float* R2  = W + o; o += (size_t)NE*128;
  float* Yb  = W + o; o += (size_t)NE*49;
  float* DV  = W + o; o += (size_t)NE;
  float* LG  = W + o; o += (size_t)NE*8;
  float* AL  = W + o; o += (size_t)NE*8;
  float* MX  = W + o; o += (size_t)NN*8;
  float* DEN = W + o; o += (size_t)NN*8;
  int* CNT = (int*)(W + o); o += NN;
  int* RP  = (int*)(W + o); o += NN + 1;
  int* EID = (int*)(W + o); o += NE;
  int* GS  = (int*)(W + o); o += NG + 1;
  // bf16 transposed weights
  u16* WB = (u16*)(W + o);
  size_t wo = 0;
  u16* T_degw2 = WB + wo; wo += 16384;
  u16* T_degw3 = WB + wo; wo += 114688;
  u16* T_ws[3]; u16* T_wt[3]; u16* T_wv[3]; u16* T_wp[3]; u16* T_rw2[3];
  for (int i = 0; i < 3; i++){ T_ws[i] = WB + wo; wo += 16384; }
  for (int i = 0; i < 3; i++){ T_wt[i] = WB + wo; wo += 16384; }
  for (int i = 0; i < 3; i++){ T_wv[i] = WB + wo; wo += 16384; }
  for (int i = 0; i < 3; i++){ T_wp[i] = WB + wo; wo += 16384; }
  for (int i = 0; i < 3; i++){ T_rw2[i] = WB + wo; wo += 16384; }
  u16* T_f1[2]; u16* T_f2[2];
  for (int i = 0; i < 2; i++){ T_f1[i] = WB + wo; wo += 65536; }
  for (int i = 0; i < 2; i++){ T_f2[i] = WB + wo; wo += 65536; }
  (void)DEN; (void)ws_size; (void)in_sizes; (void)n_in; (void)out_size;

  float* RADD = XSb;                              // E*896 = 11.0M <= XSb+XTb (15.2M)
  float* F1CH = XSb;                              // FCHUNK*49*512 = 12.85M <= XSb+XTb
  float* VCH  = Hb;                               // ECHUNK*29*128 = 11.4M <= Hb (12.8M)
  float* AG   = HR;
  float* OR_  = Hb;

  // weight casts (bf16, transposed to [N][K])
  k_cast<<<64, 256, 0, stream>>>(deg_w2, T_degw2, 128, 128);
  k_cast<<<448, 256, 0, stream>>>(deg_w3, T_degw3, 128, 896);
  for (int i = 0; i < 3; i++){
    const float* ws_ = (i < 2) ? w_src  + (size_t)i*16384 : lw_src;
    const float* wt_ = (i < 2) ? w_tgt  + (size_t)i*16384 : lw_tgt;
    const float* wv_ = (i < 2) ? w_val  + (size_t)i*16384 : lw_val;
    const float* wp_ = (i < 2) ? w_proj + (size_t)i*16384 : lw_proj;
    const float* r2_ = (i < 2) ? rad_w2 + (size_t)i*16384 : lrad_w2;
    k_cast<<<64, 256, 0, stream>>>(ws_, T_ws[i], 128, 128);
    k_cast<<<64, 256, 0, stream>>>(wt_, T_wt[i], 128, 128);
    k_cast<<<64, 256, 0, stream>>>(wv_, T_wv[i], 128, 128);
    k_cast<<<64, 256, 0, stream>>>(wp_, T_wp[i], 128, 128);
    k_cast<<<64, 256, 0, stream>>>(r2_, T_rw2[i], 128, 128);
  }
  for (int i = 0; i < 2; i++){
    k_cast<<<256, 256, 0, stream>>>(ffn_w1 + (size_t)i*65536, T_f1[i], 128, 512);
    k_cast<<<256, 256, 0, stream>>>(ffn_w2 + (size_t)i*65536, T_f2[i], 512, 128);
  }

  // CSR + groups
  k_hist<<<1, 1024, 0, stream>>>(dstp, CNT);
  k_scan2<<<1, 1024, 0, stream>>>(CNT, RP);
  k_fillw<<<NN/4, 256, 0, stream>>>(dstp, RP, EID);
  k_gstart<<<1, 32, 0, stream>>>(batch, GS);

  // geometry
  k_geom<<<48, 256, 0, stream>>>(evec, Yb, DV);

  // degree embedding MLP: 600->128 (silu) -> 128 (silu) -> 896
  k_rad1<<<NE, 128, 0, stream>>>(DV, deg_w1, deg_b1, R1);
  k_mgemm<1,0,0><<<dim3(2, NE/64), 256, 0, stream>>>(R1, T_degw2, deg_b2, R2, NE, 128, 128,
                                                     nullptr, nullptr, nullptr, nullptr, nullptr, 0);
  k_mgemm<0,0,0><<<dim3(14, NE/64), 256, 0, stream>>>(R2, T_degw3, nullptr, RADD, NE, 896, 128,
                                                      nullptr, nullptr, nullptr, nullptr, nullptr, 0);
  k_init<<<NN, 128, 0, stream>>>(pos, table, Yb, RADD, RP, EID, X);

  for (int i = 0; i < 3; i++){
    const float* nw  = (i < 2) ? attn_nw + (size_t)i*896   : fin_nw;
    const float* rw1 = (i < 2) ? rad_w1 + (size_t)i*76800 : lrad_w1;
    const float* rb1 = (i < 2) ? rad_b1 + (size_t)i*128   : lrad_b1;
    const float* av  = (i < 2) ? avec   + (size_t)i*128   : lavec;

    k_rmsnorm<<<NN, 128, 0, stream>>>(X, nw, Hb);
    k_gather<<<(NN*NRr*CD + 255)/256, 256, 0, stream>>>(Hb, HR);
    k_mgemm<0,0,0><<<dim3(2, NN*NRr/64), 256, 0, stream>>>(HR, T_ws[i], nullptr, XSb, NN*NRr, 128, 128,
                                                           nullptr, nullptr, nullptr, nullptr, nullptr, 0);
    k_mgemm<0,0,0><<<dim3(2, NN*NRr/64), 256, 0, stream>>>(HR, T_wt[i], nullptr, XTb, NN*NRr, 128, 128,
                                                           nullptr, nullptr, nullptr, nullptr, nullptr, 0);
    k_rad1<<<NE, 128, 0, stream>>>(DV, rw1, rb1, R1);
    k_mgemm<0,0,0><<<dim3(2, NE/64), 256, 0, stream>>>(R1, T_rw2[i], nullptr, R2, NE, 128, 128,
                                                       nullptr, nullptr, nullptr, nullptr, nullptr, 0);
    k_logits<<<(NE*8 + 255)/256, 256, 0, stream>>>(XSb, XTb, R2, av, srcp, dstp, LG);
    k_softmax<<<(NN*8 + 255)/256, 256, 0, stream>>>(LG, RP, EID, MX, DEN);
    k_alpha<<<(NE*8 + 255)/256, 256, 0, stream>>>(LG, MX, DEN, dstp, AL);
    for (int ch = 0; ch < NE/ECHUNK; ch++){
      int e0 = ch*ECHUNK;
      k_mgemm<0,0,1><<<dim3(2, ECHUNK*NRr/64), 256, 0, stream>>>(nullptr, T_wv[i], nullptr, VCH,
                                                                 ECHUNK*NRr, 128, 128,
                                                                 XSb, XTb, R2, srcp, dstp, e0);
      k_agg<<<dim3(NN, NRr), 128, 0, stream>>>(VCH, AL, RP, EID, e0, e0 + ECHUNK, ch == 0, AG);
    }
    k_mgemm<0,0,0><<<dim3(2, NN*NRr/64), 256, 0, stream>>>(AG, T_wp[i], nullptr, OR_, NN*NRr, 128, 128,
                                                           nullptr, nullptr, nullptr, nullptr, nullptr, 0);
    if (i < 2){
      k_scatadd<<<(NN*NRr*CD + 255)/256, 256, 0, stream>>>(OR_, X);
      k_rmsnorm<<<NN, 128, 0, stream>>>(X, ffn_nw + (size_t)i*896, Hb);
      for (int n0 = 0; n0 < NN; n0 += FCHUNK){
        const float* hA = Hb + (size_t)n0*NCO*CD;
        float* xC = X + (size_t)n0*NCO*CD;
        k_mgemm<0,0,0><<<dim3(8, FCHUNK*NCO/64), 256, 0, stream>>>(hA, T_f1[i], nullptr, F1CH,
                                                                   FCHUNK*NCO, 512, 128,
                                                                   nullptr, nullptr, nullptr, nullptr, nullptr, 0);
        k_gate<<<(FCHUNK*512 + 255)/256, 256, 0, stream>>>(F1CH, FCHUNK);
        k_mgemm<0,1,0><<<dim3(2, FCHUNK*NCO/64), 256, 0, stream>>>(F1CH, T_f2[i], nullptr, xC,
                                                                   FCHUNK*NCO, 128, 512,
                                                                   nullptr, nullptr, nullptr, nullptr, nullptr, 0);
      }
    } else {
      k_pool<<<(NG*NCO*CD + 255)/256, 256, 0, stream>>>(OR_, GS, (float*)d_out);
    }
  }
}

// Round 6
// 1623.956 us; speedup vs baseline: 3.1403x; 1.2355x over previous
//
#include <hip/hip_runtime.h>
#include <math.h>

#define NN 2048
#define NE 12288
#define NCO 49
#define NRr 29
#define CD 128
#define NG 16
#define ECHUNK 3072
#define NJOBS 21

typedef unsigned short u16;
typedef short bhalf8 __attribute__((ext_vector_type(8)));
typedef float fvec4 __attribute__((ext_vector_type(4)));

// RESTRICT: indices k (0..48) with |m|<=2.
__constant__ int c_res[29] = {0,1,2,3,4,5,6,7,8,10,11,12,13,14,18,19,20,21,22,28,29,30,31,32,40,41,42,43,44};
__constant__ int c_rinv[49] = {0,1,2,3,4,5,6,7,8,-1,9,10,11,12,13,-1,-1,-1,14,15,16,17,18,-1,-1,-1,-1,-1,19,20,21,22,23,-1,-1,-1,-1,-1,-1,-1,24,25,26,27,28,-1,-1,-1,-1};
__device__ constexpr int d_RES[29] = {0,1,2,3,4,5,6,7,8,10,11,12,13,14,18,19,20,21,22,28,29,30,31,32,40,41,42,43,44};

__device__ __forceinline__ constexpr int deg_of(int k){
  return (k<1)?0:(k<4)?1:(k<9)?2:(k<16)?3:(k<25)?4:(k<36)?5:6;
}
__device__ __forceinline__ float siluf(float x){ return x / (1.f + expf(-x)); }
__device__ __forceinline__ u16 f2bf(float f){
  unsigned int u = __float_as_uint(f);
  unsigned int r = (u + 0x7FFFu + ((u >> 16) & 1u)) >> 16;
  return (u16)r;
}
__device__ __forceinline__ unsigned int pk(u16 lo, u16 hi){ return (unsigned int)lo | ((unsigned int)hi << 16); }

// ---------------- CSR build (deterministic, parallel) ----------------
__global__ __launch_bounds__(1024) void k_hist4(const int* __restrict__ dst, int* __restrict__ cnt,
                                                int* __restrict__ CH){
  __shared__ int h[4*NN];
  for (int i = threadIdx.x; i < 4*NN; i += 1024) h[i] = 0;
  __syncthreads();
  const int QE = NE/4;
  for (int e = threadIdx.x; e < NE; e += 1024){
    int q = e / QE;
    atomicAdd(&h[q*NN + dst[e]], 1);
  }
  __syncthreads();
  for (int n = threadIdx.x; n < NN; n += 1024){
    int s = 0;
    #pragma unroll
    for (int q = 0; q < 4; q++){ int v = h[q*NN + n]; CH[q*NN + n] = v; s += v; }
    cnt[n] = s;
  }
}
__global__ __launch_bounds__(1024) void k_scan2(const int* __restrict__ cnt, int* __restrict__ rowptr){
  __shared__ int a[NN], b[NN];
  int t = threadIdx.x;
  for (int i = t; i < NN; i += 1024) a[i] = cnt[i];
  __syncthreads();
  int* pin = a; int* pout = b;
  for (int off = 1; off < NN; off <<= 1){
    for (int i = t; i < NN; i += 1024)
      pout[i] = pin[i] + ((i >= off) ? pin[i - off] : 0);
    __syncthreads();
    int* tmp = pin; pin = pout; pout = tmp;
  }
  for (int i = t; i < NN; i += 1024) rowptr[i + 1] = pin[i];
  if (t == 0) rowptr[0] = 0;
}
// node per block; wave q scans quarter q; ballot keeps increasing-e order
__global__ __launch_bounds__(256) void k_fillw4(const int* __restrict__ dst, const int* __restrict__ rowptr,
                                                const int* __restrict__ CH, int* __restrict__ eid){
  int q = threadIdx.x >> 6, lane = threadIdx.x & 63;
  int n = blockIdx.x;
  int base = rowptr[n];
  for (int qq = 0; qq < q; qq++) base += CH[qq*NN + n];
  const int QE = NE/4;
  for (int e0 = q*QE; e0 < (q+1)*QE; e0 += 64){
    int e = e0 + lane;
    bool m = (dst[e] == n);
    unsigned long long mask = __ballot(m);
    if (m) eid[base + __popcll(mask & ((1ull << lane) - 1ull))] = e;
    base += __popcll(mask);
  }
}
__global__ void k_gstart(const int* __restrict__ batch, int* __restrict__ gs){
  int g = threadIdx.x;
  if (g > NG) return;
  int lo = 0, hi = NN;
  while (lo < hi){ int mid = (lo + hi) >> 1; if (batch[mid] < g) lo = mid + 1; else hi = mid; }
  gs[g] = lo;
}

// ---------------- all weight casts in one launch: [K][N] f32 -> [N][K] bf16 ----------------
struct CastJobs {
  const float* src[NJOBS];
  u16* dst[NJOBS];
  int K[NJOBS], N[NJOBS];
  int start[NJOBS + 1];
  int total;
};
__global__ void k_castall(CastJobs J){
  int i = blockIdx.x*blockDim.x + threadIdx.x;
  if (i >= J.total) return;
  int j = 0;
  while (i >= J.start[j + 1]) j++;
  int local = i - J.start[j];
  int K = J.K[j], N = J.N[j];
  int n = local / K, k = local - n*K;
  J.dst[j][local] = f2bf(J.src[j][(size_t)k*N + n]);
}

// ---------------- geometry ----------------
__global__ void k_geom(const float* __restrict__ ev, float* __restrict__ Y, float* __restrict__ dv){
  int e = blockIdx.x*blockDim.x + threadIdx.x;
  if (e >= NE) return;
  float x = ev[e*3+0], y = ev[e*3+1], z = ev[e*3+2];
  float r = sqrtf(x*x + y*y + z*z);
  dv[e] = r;
  float rn = fmaxf(r, 1e-8f);
  float ux = x/rn, uy = y/rn, uz = z/rn;
  float ct = fminf(fmaxf(uz, -1.f), 1.f);
  float st = sqrtf(fminf(fmaxf(1.f - ct*ct, 1e-12f), 1.f));
  float phi = atan2f(uy, ux);
  float P[7][7];
  P[0][0] = 1.f;
  #pragma unroll
  for (int m = 1; m <= 6; m++) P[m][m] = -(2.f*m - 1.f)*st*P[m-1][m-1];
  #pragma unroll
  for (int m = 0; m <= 5; m++) P[m+1][m] = (2.f*m + 1.f)*ct*P[m][m];
  #pragma unroll
  for (int m = 0; m <= 6; m++){
    #pragma unroll
    for (int l = m+2; l <= 6; l++)
      P[l][m] = ((2.f*l - 1.f)*ct*P[l-1][m] - (float)(l+m-1)*P[l-2][m]) / (float)(l-m);
  }
  float cmv[7], smv[7];
  #pragma unroll
  for (int m = 0; m <= 6; m++){ cmv[m] = cosf((float)m*phi); smv[m] = sinf((float)m*phi); }
  const double FOURPI = 12.566370614359172;
  int k = 0;
  #pragma unroll
  for (int l = 0; l <= 6; l++){
    #pragma unroll
    for (int mm = -l; mm <= l; mm++){
      int am = mm < 0 ? -mm : mm;
      double ratio = 1.0;
      for (int i = l-am+1; i <= l+am; i++) ratio /= (double)i;
      double nrm = sqrt((2.0*l + 1.0)/FOURPI*ratio);
      float v;
      if (mm == 0)      v = (float)nrm * P[l][0];
      else if (mm > 0)  v = (float)(1.4142135623730951*nrm) * P[l][am] * cmv[am];
      else              v = (float)(1.4142135623730951*nrm) * P[l][am] * smv[am];
      Y[(size_t)e*49 + k] = v; k++;
    }
  }
}

// ------------- layer-1 of radial MLPs (windowed gaussian, exact) -------------
__global__ __launch_bounds__(128) void k_rad1(const float* __restrict__ dv, const float* __restrict__ Wm,
                                              const float* __restrict__ bias, float* __restrict__ out){
  int e = blockIdx.x;
  int j = threadIdx.x;
  float d = dv[e];
  const float STEPF = (float)(5.0/599.0);
  const double step_d = (double)STEPF;
  const float GC = (float)(-0.5/((2.0*step_d)*(2.0*step_d)));
  __shared__ float g[64];
  int bc = (int)rintf(d / STEPF);
  int b0 = bc - 32;
  if (j < 64){
    int b = b0 + j;
    float gg = 0.f;
    if (b >= 0 && b < 600){
      float off = (float)((double)b * (5.0/599.0));
      float t = d - off;
      gg = expf(GC*t*t);
    }
    g[j] = gg;
  }
  __syncthreads();
  float acc = bias ? bias[j] : 0.f;
  #pragma unroll 8
  for (int i = 0; i < 64; i++){
    int b = b0 + i;
    if (b >= 0 && b < 600) acc += g[i]*Wm[b*CD + j];
  }
  out[(size_t)e*CD + j] = siluf(acc);
}

// ---------------- MFMA bf16 GEMM ----------------
// AMODE: 0 = f32 A with runtime lda; 1 = fused message A; 2 = bf16 A with runtime lda.
// EPI:   0 = store (+bias); 1 = silu(+bias) store; 2 = accumulate; 3 = scatter-accum into X;
//        4 = sigmoid store; 5 = gate-mul (P0=SG) then bf16 store.
template<int AMODE, int EPI>
__global__ __launch_bounds__(256) void k_mgemm(
    const void* __restrict__ Av, const u16* __restrict__ Bt,
    const float* __restrict__ bias, void* __restrict__ Cv,
    int M, int N, int K, int lda,
    const float* __restrict__ P0, const float* __restrict__ P1,
    const float* __restrict__ P2, const int* __restrict__ src,
    const int* __restrict__ dstp, int e0)
{
  __shared__ __align__(16) u16 Asl[64*64];
  __shared__ __align__(16) u16 Bsl[64*64];
  int tid = threadIdx.x;
  int bm = blockIdx.y*64, bn = blockIdx.x*64;
  int wid = tid >> 6, lane = tid & 63;
  int wr = wid >> 1, wc = wid & 1;
  int lr = lane & 15, lk = lane >> 4;
  fvec4 acc[2][2] = {};
  for (int k0 = 0; k0 < K; k0 += 64){
    #pragma unroll
    for (int h = 0; h < 2; h++){
      int lin = tid + h*256;          // 0..511: 64 rows x 8 k-groups
      int row = lin >> 3, kg = lin & 7;
      uint4 q;
      if (AMODE == 1){
        int gr = bm + row;
        int el = gr / 29, kq = gr - el*29;
        int e = e0 + el;
        int s = src[e], t = dstp[e];
        const float* xs = P0 + ((size_t)s*29 + kq)*128 + k0 + kg*8;
        const float* xt = P1 + ((size_t)t*29 + kq)*128 + k0 + kg*8;
        const float* rd = P2 + (size_t)e*128 + k0 + kg*8;
        float v[8];
        #pragma unroll
        for (int j = 0; j < 8; j++) v[j] = (xs[j] + xt[j]) * rd[j];
        q.x = pk(f2bf(v[0]), f2bf(v[1]));
        q.y = pk(f2bf(v[2]), f2bf(v[3]));
        q.z = pk(f2bf(v[4]), f2bf(v[5]));
        q.w = pk(f2bf(v[6]), f2bf(v[7]));
      } else if (AMODE == 2){
        const u16* ap = (const u16*)Av + (size_t)(bm + row)*lda + k0 + kg*8;
        q = *(const uint4*)ap;
      } else {
        const float* ap = (const float*)Av + (size_t)(bm + row)*lda + k0 + kg*8;
        float v[8];
        #pragma unroll
        for (int j = 0; j < 8; j++) v[j] = ap[j];
        q.x = pk(f2bf(v[0]), f2bf(v[1]));
        q.y = pk(f2bf(v[2]), f2bf(v[3]));
        q.z = pk(f2bf(v[4]), f2bf(v[5]));
        q.w = pk(f2bf(v[6]), f2bf(v[7]));
      }
      *(uint4*)&Asl[row*64 + ((kg*8) ^ ((row & 7)*8))] = q;
      const u16* bp = Bt + (size_t)(bn + row)*K + k0 + kg*8;
      *(uint4*)&Bsl[row*64 + ((kg*8) ^ ((row & 7)*8))] = *(const uint4*)bp;
    }
    __syncthreads();
    #pragma unroll
    for (int ks = 0; ks < 2; ks++){
      bhalf8 af[2], bfr[2];
      int kg = ks*4 + lk;
      #pragma unroll
      for (int mi = 0; mi < 2; mi++){
        int ar = wr*32 + mi*16 + lr;
        af[mi] = *(const bhalf8*)&Asl[ar*64 + ((kg*8) ^ ((ar & 7)*8))];
      }
      #pragma unroll
      for (int ni = 0; ni < 2; ni++){
        int br = wc*32 + ni*16 + lr;
        bfr[ni] = *(const bhalf8*)&Bsl[br*64 + ((kg*8) ^ ((br & 7)*8))];
      }
      #pragma unroll
      for (int mi = 0; mi < 2; mi++)
        #pragma unroll
        for (int ni = 0; ni < 2; ni++)
          acc[mi][ni] = __builtin_amdgcn_mfma_f32_16x16x32_bf16(af[mi], bfr[ni], acc[mi][ni], 0, 0, 0);
    }
    __syncthreads();
  }
  #pragma unroll
  for (int mi = 0; mi < 2; mi++){
    #pragma unroll
    for (int ni = 0; ni < 2; ni++){
      #pragma unroll
      for (int j = 0; j < 4; j++){
        int row = bm + wr*32 + mi*16 + lk*4 + j;
        int col = bn + wc*32 + ni*16 + lr;
        float v = acc[mi][ni][j];
        if (EPI == 0){
          if (bias) v += bias[col];
          ((float*)Cv)[(size_t)row*N + col] = v;
        } else if (EPI == 1){
          if (bias) v += bias[col];
          ((float*)Cv)[(size_t)row*N + col] = siluf(v);
        } else if (EPI == 2){
          ((float*)Cv)[(size_t)row*N + col] += v;
        } else if (EPI == 3){
          int n = row / 29, kr = row - n*29;
          ((float*)Cv)[((size_t)n*49 + c_res[kr])*128 + col] += v;
        } else if (EPI == 4){
          ((float*)Cv)[(size_t)row*N + col] = 1.f/(1.f + expf(-v));
        } else {
          float g = P0[(size_t)(row/49)*N + col];
          ((u16*)Cv)[(size_t)row*N + col] = f2bf(v*g);
        }
      }
    }
  }
}

// ---------------- node init ----------------
__global__ __launch_bounds__(128) void k_init(const float* __restrict__ pos, const float* __restrict__ table,
                                              const float* __restrict__ Yb, const float* __restrict__ radd,
                                              const int* __restrict__ rowptr, const int* __restrict__ eid,
                                              float* __restrict__ x){
  int n = blockIdx.x;
  int c = threadIdx.x;
  const float DLO = -3.26267f;
  const float DRG = (float)(3.295396 - (-3.26267));
  float p0 = pos[n*3+0], p1 = pos[n*3+1], p2 = pos[n*3+2];
  int t0 = min(127, max(0, (int)rintf((p0 - DLO)/DRG*128.f - 0.5f)));
  int t1 = min(127, max(0, (int)rintf((p1 - DLO)/DRG*128.f - 0.5f)));
  int t2 = min(127, max(0, (int)rintf((p2 - DLO)/DRG*128.f - 0.5f)));
  float emb = table[t0*CD + c] + table[t1*CD + c] + table[t2*CD + c];
  __shared__ float Yl[49];
  __shared__ float rl[896];
  float acc[NCO];
  #pragma unroll
  for (int k = 0; k < NCO; k++) acc[k] = 0.f;
  int pA = rowptr[n], pB = rowptr[n+1];
  for (int p = pA; p < pB; p++){
    int e = eid[p];
    if (c < 49) Yl[c] = Yb[(size_t)e*49 + c];
    #pragma unroll
    for (int q = 0; q < 7; q++) rl[q*128 + c] = radd[(size_t)e*896 + q*128 + c];
    __syncthreads();
    #pragma unroll
    for (int k = 0; k < NCO; k++){
      acc[k] += Yl[k]*rl[deg_of(k)*128 + c];
    }
    __syncthreads();
  }
  size_t base = (size_t)n*NCO*CD;
  x[base + c] = emb + acc[0]*(1.f/3.f);
  #pragma unroll
  for (int k = 1; k < NCO; k++) x[base + k*CD + c] = acc[k]*(1.f/3.f);
}

// ---------------- degree-grouped RMS norm (full 49 rows, for FFN) ----------------
__global__ __launch_bounds__(128) void k_rmsnorm(const float* __restrict__ x, const float* __restrict__ w,
                                                 float* __restrict__ out){
  int n = blockIdx.x;
  int c = threadIdx.x;
  const float* xb = x + (size_t)n*NCO*CD;
  float vals[NCO];
  float ss[7] = {0,0,0,0,0,0,0};
  #pragma unroll
  for (int k = 0; k < NCO; k++){
    float v = xb[k*CD + c];
    vals[k] = v;
    ss[deg_of(k)] += v*v;
  }
  __shared__ float red[7][128];
  #pragma unroll
  for (int l = 0; l < 7; l++) red[l][c] = ss[l];
  __syncthreads();
  __shared__ float inv[7];
  if (c < 7){
    float s = 0.f;
    for (int i = 0; i < 128; i++) s += red[c][i];
    float ms = s / ((float)(2*c + 1)*128.f);
    inv[c] = 1.f / sqrtf(ms + 1e-6f);
  }
  __syncthreads();
  size_t base = (size_t)n*NCO*CD;
  #pragma unroll
  for (int k = 0; k < NCO; k++){
    int l = deg_of(k);
    out[base + k*CD + c] = vals[k]*inv[l]*w[l*CD + c];
  }
}

// ---------------- RMS norm writing restricted 29 rows directly ----------------
__global__ __launch_bounds__(128) void k_rmsnormR(const float* __restrict__ x, const float* __restrict__ w,
                                                  float* __restrict__ hr){
  int n = blockIdx.x;
  int c = threadIdx.x;
  const float* xb = x + (size_t)n*NCO*CD;
  float vals[NCO];
  float ss[7] = {0,0,0,0,0,0,0};
  #pragma unroll
  for (int k = 0; k < NCO; k++){
    float v = xb[k*CD + c];
    vals[k] = v;
    ss[deg_of(k)] += v*v;
  }
  __shared__ float red[7][128];
  #pragma unroll
  for (int l = 0; l < 7; l++) red[l][c] = ss[l];
  __syncthreads();
  __shared__ float inv[7];
  if (c < 7){
    float s = 0.f;
    for (int i = 0; i < 128; i++) s += red[c][i];
    float ms = s / ((float)(2*c + 1)*128.f);
    inv[c] = 1.f / sqrtf(ms + 1e-6f);
  }
  __syncthreads();
  size_t base = (size_t)n*NRr*CD;
  #pragma unroll
  for (int kr = 0; kr < NRr; kr++){
    int k = d_RES[kr];
    int l = deg_of(k);
    hr[base + kr*CD + c] = vals[k]*inv[l]*w[l*CD + c];
  }
}

// ---------------- attention small kernels ----------------
__global__ void k_logits(const float* __restrict__ XS, const float* __restrict__ XT,
                         const float* __restrict__ rad, const float* __restrict__ avec,
                         const int* __restrict__ src, const int* __restrict__ dst,
                         float* __restrict__ lg){
  int idx = blockIdx.x*blockDim.x + threadIdx.x;
  if (idx >= NE*8) return;
  int e = idx >> 3, hh = idx & 7;
  int s = src[e], t = dst[e];
  float acc = 0.f;
  #pragma unroll
  for (int dd = 0; dd < 16; dd++){
    int j = hh*16 + dd;
    float m = (XS[(size_t)s*NRr*CD + j] + XT[(size_t)t*NRr*CD + j]) * rad[(size_t)e*CD + j];
    acc += siluf(m)*avec[hh*16 + dd];
  }
  lg[idx] = acc;
}
__global__ void k_softmax(const float* __restrict__ lg, const int* __restrict__ rowptr,
                          const int* __restrict__ eid, float* __restrict__ mx, float* __restrict__ den){
  int idx = blockIdx.x*blockDim.x + threadIdx.x;
  if (idx >= NN*8) return;
  int n = idx >> 3, hh = idx & 7;
  int p0 = rowptr[n], p1 = rowptr[n+1];
  float m = -1e30f;
  for (int p = p0; p < p1; p++) m = fmaxf(m, lg[eid[p]*8 + hh]);
  float s = 0.f;
  for (int p = p0; p < p1; p++) s += expf(lg[eid[p]*8 + hh] - m);
  mx[idx] = m; den[idx] = s;
}
// aggregation with alpha computed in-register from lg/mx/den
__global__ __launch_bounds__(128) void k_agg(const float* __restrict__ V, const float* __restrict__ lg,
                                             const float* __restrict__ mx, const float* __restrict__ den,
                                             const int* __restrict__ rowptr, const int* __restrict__ eid,
                                             int e0, int e1, int first, float* __restrict__ agg){
  int n = blockIdx.x;
  int k = blockIdx.y;
  int c = threadIdx.x;
  size_t oidx = ((size_t)n*NRr + k)*CD + c;
  float s = first ? 0.f : agg[oidx];
  int hh = c >> 4;
  float m = mx[n*8 + hh];
  float inv = 1.f / fmaxf(den[n*8 + hh], 1e-9f);
  int p0 = rowptr[n], p1 = rowptr[n+1];
  for (int p = p0; p < p1; p++){
    int e = eid[p];
    if (e < e0 || e >= e1) continue;
    float a = expf(lg[e*8 + hh] - m) * inv;
    s += a*V[((size_t)(e - e0)*NRr + k)*CD + c];
  }
  agg[oidx] = s;
}

// ---------------- pooling ----------------
__global__ void k_pool(const float* __restrict__ orr, const int* __restrict__ gs, float* __restrict__ out){
  int i = blockIdx.x*blockDim.x + threadIdx.x;
  if (i >= NG*NCO*CD) return;
  int c = i & 127;
  int k = (i >> 7) % 49;
  int g = i / (49*128);
  int kr = c_rinv[k];
  float v = 0.f;
  if (kr >= 0){
    int a = gs[g], b = gs[g+1];
    float s = 0.f;
    for (int n = a; n < b; n++) s += orr[((size_t)n*29 + kr)*128 + c];
    int cnt = b - a;
    v = s / (float)(cnt > 0 ? cnt : 1);
  }
  out[i] = v;
}

extern "C" void kernel_launch(void* const* d_in, const int* in_sizes, int n_in,
                              void* d_out, int out_size, void* d_ws, size_t ws_size,
                              hipStream_t stream){
  const float* pos    = (const float*)d_in[0];
  const float* evec   = (const float*)d_in[1];
  const int*   eidx   = (const int*)  d_in[2];
  const int*   batch  = (const int*)  d_in[3];
  const float* table  = (const float*)d_in[4];
  const float* deg_w1 = (const float*)d_in[5];
  const float* deg_b1 = (const float*)d_in[6];
  const float* deg_w2 = (const float*)d_in[7];
  const float* deg_b2 = (const float*)d_in[8];
  const float* deg_w3 = (const float*)d_in[9];
  const float* attn_nw= (const float*)d_in[10];
  const float* w_src  = (const float*)d_in[11];
  const float* w_tgt  = (const float*)d_in[12];
  const float* rad_w1 = (const float*)d_in[13];
  const float* rad_b1 = (const float*)d_in[14];
  const float* rad_w2 = (const float*)d_in[15];
  const float* avec   = (const float*)d_in[16];
  const float* w_val  = (const float*)d_in[17];
  const float* w_proj = (const float*)d_in[18];
  const float* ffn_nw = (const float*)d_in[19];
  const float* ffn_w1 = (const float*)d_in[20];
  const float* ffn_w2 = (const float*)d_in[21];
  const float* fin_nw = (const float*)d_in[22];
  const float* lw_src = (const float*)d_in[23];
  const float* lw_tgt = (const float*)d_in[24];
  const float* lrad_w1= (const float*)d_in[25];
  const float* lrad_b1= (const float*)d_in[26];
  const float* lrad_w2= (const float*)d_in[27];
  const float* lavec  = (const float*)d_in[28];
  const float* lw_val = (const float*)d_in[29];
  const float* lw_proj= (const float*)d_in[30];

  const int* srcp = eidx;
  const int* dstp = eidx + NE;

  float* W = (float*)d_ws;
  size_t o = 0;
  float* X   = W + o; o += (size_t)NN*49*128;
  float* Hb  = W + o; o += (size_t)NN*49*128;   // also V chunks, latent proj out
  float* HR  = W + o; o += (size_t)NN*29*128;   // also agg; start of FFN hidden (bf16)
  float* XSb = W + o; o += (size_t)NN*29*128;   // also rad_deg part; FFN hidden spill
  float* XTb = W + o; o += (size_t)NN*29*128;
  float* R1  = W + o; o += (size_t)NE*128;
  float* R2  = W + o; o += (size_t)NE*128;
  float* Yb  = W + o; o += (size_t)NE*49;
  float* DV  = W + o; o += (size_t)NE;
  float* LG  = W + o; o += (size_t)NE*8;
  float* MX  = W + o; o += (size_t)NN*8;
  float* DEN = W + o; o += (size_t)NN*8;
  float* SG  = W + o; o += (size_t)NN*512;
  int* CNT = (int*)(W + o); o += NN;
  int* RP  = (int*)(W + o); o += NN + 1;
  int* EID = (int*)(W + o); o += NE;
  int* GS  = (int*)(W + o); o += NG + 1;
  int* CH  = (int*)(W + o); o += 4*NN;
  // bf16 transposed weights
  u16* WB = (u16*)(W + o);
  size_t wo = 0;
  u16* T_degw2 = WB + wo; wo += 16384;
  u16* T_degw3 = WB + wo; wo += 114688;
  u16* T_ws[3]; u16* T_wt[3]; u16* T_wv[3]; u16* T_wp[3]; u16* T_rw2[3];
  for (int i = 0; i < 3; i++){ T_ws[i] = WB + wo; wo += 16384; }
  for (int i = 0; i < 3; i++){ T_wt[i] = WB + wo; wo += 16384; }
  for (int i = 0; i < 3; i++){ T_wv[i] = WB + wo; wo += 16384; }
  for (int i = 0; i < 3; i++){ T_wp[i] = WB + wo; wo += 16384; }
  for (int i = 0; i < 3; i++){ T_rw2[i] = WB + wo; wo += 16384; }
  u16* T_f1[2]; u16* T_f2[2];
  for (int i = 0; i < 2; i++){ T_f1[i] = WB + wo; wo += 65536; }
  for (int i = 0; i < 2; i++){ T_f2[i] = WB + wo; wo += 65536; }
  (void)ws_size; (void)in_sizes; (void)n_in; (void)out_size;

  float* RADD = XSb;                              // E*896 = 11.0M <= XSb+XTb (15.2M)
  float* VCH  = Hb;                               // ECHUNK*29*128 = 11.4M <= Hb (12.8M)
  float* AG   = HR;
  float* OR_  = Hb;                               // latent proj out
  u16*  F1B   = (u16*)HR;                         // 1024*49*512 u16 = 25.7M u16 <= HR+XSb (30.4M u16)

  // ---- all weight casts in one launch ----
  {
    CastJobs J;
    int idx = 0, acc = 0;
    auto add = [&](const float* s, u16* d, int K, int N){
      J.src[idx] = s; J.dst[idx] = d; J.K[idx] = K; J.N[idx] = N; J.start[idx] = acc;
      acc += K*N; idx++;
    };
    add(deg_w2, T_degw2, 128, 128);
    add(deg_w3, T_degw3, 128, 896);
    for (int i = 0; i < 3; i++){
      add((i < 2) ? w_src  + (size_t)i*16384 : lw_src,  T_ws[i], 128, 128);
      add((i < 2) ? w_tgt  + (size_t)i*16384 : lw_tgt,  T_wt[i], 128, 128);
      add((i < 2) ? w_val  + (size_t)i*16384 : lw_val,  T_wv[i], 128, 128);
      add((i < 2) ? w_proj + (size_t)i*16384 : lw_proj, T_wp[i], 128, 128);
      add((i < 2) ? rad_w2 + (size_t)i*16384 : lrad_w2, T_rw2[i], 128, 128);
    }
    for (int i = 0; i < 2; i++){
      add(ffn_w1 + (size_t)i*65536, T_f1[i], 128, 512);
      add(ffn_w2 + (size_t)i*65536, T_f2[i], 512, 128);
    }
    J.start[idx] = acc; J.total = acc;
    k_castall<<<(acc + 255)/256, 256, 0, stream>>>(J);
  }

  // CSR + groups
  k_hist4<<<1, 1024, 0, stream>>>(dstp, CNT, CH);
  k_scan2<<<1, 1024, 0, stream>>>(CNT, RP);
  k_fillw4<<<NN, 256, 0, stream>>>(dstp, RP, CH, EID);
  k_gstart<<<1, 32, 0, stream>>>(batch, GS);

  // geometry
  k_geom<<<48, 256, 0, stream>>>(evec, Yb, DV);

  // degree embedding MLP: 600->128 (silu) -> 128 (silu) -> 896
  k_rad1<<<NE, 128, 0, stream>>>(DV, deg_w1, deg_b1, R1);
  k_mgemm<0,1><<<dim3(2, NE/64), 256, 0, stream>>>(R1, T_degw2, deg_b2, R2, NE, 128, 128, 128,
                                                   nullptr, nullptr, nullptr, nullptr, nullptr, 0);
  k_mgemm<0,0><<<dim3(14, NE/64), 256, 0, stream>>>(R2, T_degw3, nullptr, RADD, NE, 896, 128, 128,
                                                    nullptr, nullptr, nullptr, nullptr, nullptr, 0);
  k_init<<<NN, 128, 0, stream>>>(pos, table, Yb, RADD, RP, EID, X);

  for (int i = 0; i < 3; i++){
    const float* nw  = (i < 2) ? attn_nw + (size_t)i*896   : fin_nw;
    const float* rw1 = (i < 2) ? rad_w1 + (size_t)i*76800 : lrad_w1;
    const float* rb1 = (i < 2) ? rad_b1 + (size_t)i*128   : lrad_b1;
    const float* av  = (i < 2) ? avec   + (size_t)i*128   : lavec;

    k_rmsnormR<<<NN, 128, 0, stream>>>(X, nw, HR);
    k_mgemm<0,0><<<dim3(2, NN*NRr/64), 256, 0, stream>>>(HR, T_ws[i], nullptr, XSb, NN*NRr, 128, 128, 128,
                                                         nullptr, nullptr, nullptr, nullptr, nullptr, 0);
    k_mgemm<0,0><<<dim3(2, NN*NRr/64), 256, 0, stream>>>(HR, T_wt[i], nullptr, XTb, NN*NRr, 128, 128, 128,
                                                         nullptr, nullptr, nullptr, nullptr, nullptr, 0);
    k_rad1<<<NE, 128, 0, stream>>>(DV, rw1, rb1, R1);
    k_mgemm<0,0><<<dim3(2, NE/64), 256, 0, stream>>>(R1, T_rw2[i], nullptr, R2, NE, 128, 128, 128,
                                                     nullptr, nullptr, nullptr, nullptr, nullptr, 0);
    k_logits<<<(NE*8 + 255)/256, 256, 0, stream>>>(XSb, XTb, R2, av, srcp, dstp, LG);
    k_softmax<<<(NN*8 + 255)/256, 256, 0, stream>>>(LG, RP, EID, MX, DEN);
    for (int ch = 0; ch < NE/ECHUNK; ch++){
      int e0 = ch*ECHUNK;
      k_mgemm<1,0><<<dim3(2, ECHUNK*NRr/64), 256, 0, stream>>>(nullptr, T_wv[i], nullptr, VCH,
                                                               ECHUNK*NRr, 128, 128, 128,
                                                               XSb, XTb, R2, srcp, dstp, e0);
      k_agg<<<dim3(NN, NRr), 128, 0, stream>>>(VCH, LG, MX, DEN, RP, EID, e0, e0 + ECHUNK, ch == 0, AG);
    }
    if (i < 2){
      // projection with fused scatter-accumulate into X
      k_mgemm<0,3><<<dim3(2, NN*NRr/64), 256, 0, stream>>>(AG, T_wp[i], nullptr, X, NN*NRr, 128, 128, 128,
                                                           nullptr, nullptr, nullptr, nullptr, nullptr, 0);
      // FFN: h_gated[n,k,:] = (x@w1)[n,k,:] * sigmoid((x@w1)[n,0,:])
      k_rmsnorm<<<NN, 128, 0, stream>>>(X, ffn_nw + (size_t)i*896, Hb);
      k_mgemm<0,4><<<dim3(8, NN/64), 256, 0, stream>>>(Hb, T_f1[i], nullptr, SG, NN, 512, 128, NCO*CD,
                                                       nullptr, nullptr, nullptr, nullptr, nullptr, 0);
      for (int half = 0; half < 2; half++){
        int n0 = half*(NN/2);
        int Mh = (NN/2)*NCO;   // 50176
        k_mgemm<0,5><<<dim3(8, Mh/64), 256, 0, stream>>>(Hb + (size_t)n0*NCO*CD, T_f1[i], nullptr, F1B,
                                                         Mh, 512, 128, 128,
                                                         SG + (size_t)n0*512, nullptr, nullptr, nullptr, nullptr, 0);
        k_mgemm<2,2><<<dim3(2, Mh/64), 256, 0, stream>>>(F1B, T_f2[i], nullptr, X + (size_t)n0*NCO*CD,
                                                         Mh, 128, 512, 512,
                                                         nullptr, nullptr, nullptr, nullptr, nullptr, 0);
      }
    } else {
      k_mgemm<0,0><<<dim3(2, NN*NRr/64), 256, 0, stream>>>(AG, T_wp[i], nullptr, OR_, NN*NRr, 128, 128, 128,
                                                           nullptr, nullptr, nullptr, nullptr, nullptr, 0);
      k_pool<<<(NG*NCO*CD + 255)/256, 256, 0, stream>>>(OR_, GS, (float*)d_out);
    }
  }
}

// Round 7
// 1434.258 us; speedup vs baseline: 3.5557x; 1.1323x over previous
//
#include <hip/hip_runtime.h>
#include <math.h>

#define NN 2048
#define NE 12288
#define NCO 49
#define NRr 29
#define CD 128
#define NG 16
#define ECHUNK 3072
#define NJOBS 21

typedef unsigned short u16;
typedef short bhalf8 __attribute__((ext_vector_type(8)));
typedef float fvec4 __attribute__((ext_vector_type(4)));

// RESTRICT: indices k (0..48) with |m|<=2.
__constant__ int c_res[29] = {0,1,2,3,4,5,6,7,8,10,11,12,13,14,18,19,20,21,22,28,29,30,31,32,40,41,42,43,44};
__constant__ int c_rinv[49] = {0,1,2,3,4,5,6,7,8,-1,9,10,11,12,13,-1,-1,-1,14,15,16,17,18,-1,-1,-1,-1,-1,19,20,21,22,23,-1,-1,-1,-1,-1,-1,-1,24,25,26,27,28,-1,-1,-1,-1};
__device__ constexpr int d_RES[29] = {0,1,2,3,4,5,6,7,8,10,11,12,13,14,18,19,20,21,22,28,29,30,31,32,40,41,42,43,44};

__device__ __forceinline__ constexpr int deg_of(int k){
  return (k<1)?0:(k<4)?1:(k<9)?2:(k<16)?3:(k<25)?4:(k<36)?5:6;
}
__device__ __forceinline__ float siluf(float x){ return x / (1.f + expf(-x)); }
__device__ __forceinline__ u16 f2bf(float f){
  unsigned int u = __float_as_uint(f);
  unsigned int r = (u + 0x7FFFu + ((u >> 16) & 1u)) >> 16;
  return (u16)r;
}
__device__ __forceinline__ unsigned int pk(u16 lo, u16 hi){ return (unsigned int)lo | ((unsigned int)hi << 16); }

// ---------------- CSR build (deterministic, parallel) ----------------
__global__ __launch_bounds__(1024) void k_hist4(const int* __restrict__ dst, int* __restrict__ cnt,
                                                int* __restrict__ CH){
  __shared__ int h[4*NN];
  for (int i = threadIdx.x; i < 4*NN; i += 1024) h[i] = 0;
  __syncthreads();
  const int QE = NE/4;
  for (int e = threadIdx.x; e < NE; e += 1024){
    int q = e / QE;
    atomicAdd(&h[q*NN + dst[e]], 1);
  }
  __syncthreads();
  for (int n = threadIdx.x; n < NN; n += 1024){
    int s = 0;
    #pragma unroll
    for (int q = 0; q < 4; q++){ int v = h[q*NN + n]; CH[q*NN + n] = v; s += v; }
    cnt[n] = s;
  }
}
__global__ __launch_bounds__(1024) void k_scan2(const int* __restrict__ cnt, int* __restrict__ rowptr){
  __shared__ int a[NN], b[NN];
  int t = threadIdx.x;
  for (int i = t; i < NN; i += 1024) a[i] = cnt[i];
  __syncthreads();
  int* pin = a; int* pout = b;
  for (int off = 1; off < NN; off <<= 1){
    for (int i = t; i < NN; i += 1024)
      pout[i] = pin[i] + ((i >= off) ? pin[i - off] : 0);
    __syncthreads();
    int* tmp = pin; pin = pout; pout = tmp;
  }
  for (int i = t; i < NN; i += 1024) rowptr[i + 1] = pin[i];
  if (t == 0) rowptr[0] = 0;
}
__global__ __launch_bounds__(256) void k_fillw4(const int* __restrict__ dst, const int* __restrict__ rowptr,
                                                const int* __restrict__ CH, int* __restrict__ eid){
  int q = threadIdx.x >> 6, lane = threadIdx.x & 63;
  int n = blockIdx.x;
  int base = rowptr[n];
  for (int qq = 0; qq < q; qq++) base += CH[qq*NN + n];
  const int QE = NE/4;
  for (int e0 = q*QE; e0 < (q+1)*QE; e0 += 64){
    int e = e0 + lane;
    bool m = (dst[e] == n);
    unsigned long long mask = __ballot(m);
    if (m) eid[base + __popcll(mask & ((1ull << lane) - 1ull))] = e;
    base += __popcll(mask);
  }
}
__global__ void k_gstart(const int* __restrict__ batch, int* __restrict__ gs){
  int g = threadIdx.x;
  if (g > NG) return;
  int lo = 0, hi = NN;
  while (lo < hi){ int mid = (lo + hi) >> 1; if (batch[mid] < g) lo = mid + 1; else hi = mid; }
  gs[g] = lo;
}

// ---------------- all weight casts in one launch: [K][N] f32 -> [N][K] bf16 ----------------
struct CastJobs {
  const float* src[NJOBS];
  u16* dst[NJOBS];
  int K[NJOBS], N[NJOBS];
  int start[NJOBS + 1];
  int total;
};
__global__ void k_castall(CastJobs J){
  int i = blockIdx.x*blockDim.x + threadIdx.x;
  if (i >= J.total) return;
  int j = 0;
  while (i >= J.start[j + 1]) j++;
  int local = i - J.start[j];
  int K = J.K[j], N = J.N[j];
  int n = local / K, k = local - n*K;
  J.dst[j][local] = f2bf(J.src[j][(size_t)k*N + n]);
}

// ---------------- geometry ----------------
__global__ void k_geom(const float* __restrict__ ev, float* __restrict__ Y, float* __restrict__ dv){
  int e = blockIdx.x*blockDim.x + threadIdx.x;
  if (e >= NE) return;
  float x = ev[e*3+0], y = ev[e*3+1], z = ev[e*3+2];
  float r = sqrtf(x*x + y*y + z*z);
  dv[e] = r;
  float rn = fmaxf(r, 1e-8f);
  float ux = x/rn, uy = y/rn, uz = z/rn;
  float ct = fminf(fmaxf(uz, -1.f), 1.f);
  float st = sqrtf(fminf(fmaxf(1.f - ct*ct, 1e-12f), 1.f));
  float phi = atan2f(uy, ux);
  float P[7][7];
  P[0][0] = 1.f;
  #pragma unroll
  for (int m = 1; m <= 6; m++) P[m][m] = -(2.f*m - 1.f)*st*P[m-1][m-1];
  #pragma unroll
  for (int m = 0; m <= 5; m++) P[m+1][m] = (2.f*m + 1.f)*ct*P[m][m];
  #pragma unroll
  for (int m = 0; m <= 6; m++){
    #pragma unroll
    for (int l = m+2; l <= 6; l++)
      P[l][m] = ((2.f*l - 1.f)*ct*P[l-1][m] - (float)(l+m-1)*P[l-2][m]) / (float)(l-m);
  }
  float cmv[7], smv[7];
  #pragma unroll
  for (int m = 0; m <= 6; m++){ cmv[m] = cosf((float)m*phi); smv[m] = sinf((float)m*phi); }
  const double FOURPI = 12.566370614359172;
  int k = 0;
  #pragma unroll
  for (int l = 0; l <= 6; l++){
    #pragma unroll
    for (int mm = -l; mm <= l; mm++){
      int am = mm < 0 ? -mm : mm;
      double ratio = 1.0;
      for (int i = l-am+1; i <= l+am; i++) ratio /= (double)i;
      double nrm = sqrt((2.0*l + 1.0)/FOURPI*ratio);
      float v;
      if (mm == 0)      v = (float)nrm * P[l][0];
      else if (mm > 0)  v = (float)(1.4142135623730951*nrm) * P[l][am] * cmv[am];
      else              v = (float)(1.4142135623730951*nrm) * P[l][am] * smv[am];
      Y[(size_t)e*49 + k] = v; k++;
    }
  }
}

// ------------- layer-1 of radial MLPs (windowed gaussian, exact) -------------
__global__ __launch_bounds__(128) void k_rad1(const float* __restrict__ dv, const float* __restrict__ Wm,
                                              const float* __restrict__ bias, float* __restrict__ out){
  int e = blockIdx.x;
  int j = threadIdx.x;
  float d = dv[e];
  const float STEPF = (float)(5.0/599.0);
  const double step_d = (double)STEPF;
  const float GC = (float)(-0.5/((2.0*step_d)*(2.0*step_d)));
  __shared__ float g[64];
  int bc = (int)rintf(d / STEPF);
  int b0 = bc - 32;
  if (j < 64){
    int b = b0 + j;
    float gg = 0.f;
    if (b >= 0 && b < 600){
      float off = (float)((double)b * (5.0/599.0));
      float t = d - off;
      gg = expf(GC*t*t);
    }
    g[j] = gg;
  }
  __syncthreads();
  float acc = bias ? bias[j] : 0.f;
  #pragma unroll 8
  for (int i = 0; i < 64; i++){
    int b = b0 + i;
    if (b >= 0 && b < 600) acc += g[i]*Wm[b*CD + j];
  }
  out[(size_t)e*CD + j] = siluf(acc);
}

// ---------------- MFMA bf16 GEMM with NT column-tiles per block ----------------
// AMODE: 0 = f32 A (runtime lda); 1 = fused message A (P0 = XST, stride 256); 2 = bf16 A (runtime lda).
// EPI:   0 store(+bias); 1 silu(+bias); 2 accumulate; 3 scatter-accum into X;
//        4 sigmoid store; 5 gate-mul (P0=SG) then bf16 store.
template<int AMODE, int EPI, int NT>
__global__ __launch_bounds__(256) void k_mgemm(
    const void* __restrict__ Av, const u16* __restrict__ Bt,
    const float* __restrict__ bias, void* __restrict__ Cv,
    int M, int N, int K, int lda,
    const float* __restrict__ P0,
    const int* __restrict__ src, const int* __restrict__ dstp, int e0)
{
  __shared__ __align__(16) u16 Asl[64*64];
  __shared__ __align__(16) u16 Bsl[NT][64*64];
  int tid = threadIdx.x;
  int bm = blockIdx.y*64;
  int bn0 = blockIdx.x*NT*64;
  int wid = tid >> 6, lane = tid & 63;
  int wr = wid >> 1, wc = wid & 1;
  int lr = lane & 15, lk = lane >> 4;
  fvec4 acc[NT][2][2] = {};
  for (int k0 = 0; k0 < K; k0 += 64){
    #pragma unroll
    for (int h = 0; h < 2; h++){
      int lin = tid + h*256;          // 0..511: 64 rows x 8 k-groups
      int row = lin >> 3, kg = lin & 7;
      uint4 q;
      if (AMODE == 1){
        int gr = bm + row;
        int el = gr / 29, kq = gr - el*29;
        int e = e0 + el;
        int s = src[e], t = dstp[e];
        const float* xs = P0 + ((size_t)s*29 + kq)*256 + k0 + kg*8;
        const float* xt = P0 + ((size_t)t*29 + kq)*256 + 128 + k0 + kg*8;
        const float* rd = (const float*)Av + (size_t)e*128 + k0 + kg*8;
        float v[8];
        #pragma unroll
        for (int j = 0; j < 8; j++) v[j] = (xs[j] + xt[j]) * rd[j];
        q.x = pk(f2bf(v[0]), f2bf(v[1]));
        q.y = pk(f2bf(v[2]), f2bf(v[3]));
        q.z = pk(f2bf(v[4]), f2bf(v[5]));
        q.w = pk(f2bf(v[6]), f2bf(v[7]));
      } else if (AMODE == 2){
        const u16* ap = (const u16*)Av + (size_t)(bm + row)*lda + k0 + kg*8;
        q = *(const uint4*)ap;
      } else {
        const float* ap = (const float*)Av + (size_t)(bm + row)*lda + k0 + kg*8;
        float v[8];
        #pragma unroll
        for (int j = 0; j < 8; j++) v[j] = ap[j];
        q.x = pk(f2bf(v[0]), f2bf(v[1]));
        q.y = pk(f2bf(v[2]), f2bf(v[3]));
        q.z = pk(f2bf(v[4]), f2bf(v[5]));
        q.w = pk(f2bf(v[6]), f2bf(v[7]));
      }
      *(uint4*)&Asl[row*64 + ((kg*8) ^ ((row & 7)*8))] = q;
    }
    #pragma unroll
    for (int t = 0; t < NT; t++){
      #pragma unroll
      for (int h = 0; h < 2; h++){
        int lin = tid + h*256;
        int row = lin >> 3, kg = lin & 7;
        const u16* bp = Bt + (size_t)(bn0 + t*64 + row)*K + k0 + kg*8;
        *(uint4*)&Bsl[t][row*64 + ((kg*8) ^ ((row & 7)*8))] = *(const uint4*)bp;
      }
    }
    __syncthreads();
    #pragma unroll
    for (int ks = 0; ks < 2; ks++){
      int kg = ks*4 + lk;
      bhalf8 af[2];
      #pragma unroll
      for (int mi = 0; mi < 2; mi++){
        int ar = wr*32 + mi*16 + lr;
        af[mi] = *(const bhalf8*)&Asl[ar*64 + ((kg*8) ^ ((ar & 7)*8))];
      }
      #pragma unroll
      for (int t = 0; t < NT; t++){
        bhalf8 bfr[2];
        #pragma unroll
        for (int ni = 0; ni < 2; ni++){
          int br = wc*32 + ni*16 + lr;
          bfr[ni] = *(const bhalf8*)&Bsl[t][br*64 + ((kg*8) ^ ((br & 7)*8))];
        }
        #pragma unroll
        for (int mi = 0; mi < 2; mi++)
          #pragma unroll
          for (int ni = 0; ni < 2; ni++)
            acc[t][mi][ni] = __builtin_amdgcn_mfma_f32_16x16x32_bf16(af[mi], bfr[ni], acc[t][mi][ni], 0, 0, 0);
      }
    }
    __syncthreads();
  }
  #pragma unroll
  for (int t = 0; t < NT; t++){
    #pragma unroll
    for (int mi = 0; mi < 2; mi++){
      #pragma unroll
      for (int ni = 0; ni < 2; ni++){
        #pragma unroll
        for (int j = 0; j < 4; j++){
          int row = bm + wr*32 + mi*16 + lk*4 + j;
          int col = bn0 + t*64 + wc*32 + ni*16 + lr;
          float v = acc[t][mi][ni][j];
          if (EPI == 0){
            if (bias) v += bias[col];
            ((float*)Cv)[(size_t)row*N + col] = v;
          } else if (EPI == 1){
            if (bias) v += bias[col];
            ((float*)Cv)[(size_t)row*N + col] = siluf(v);
          } else if (EPI == 2){
            ((float*)Cv)[(size_t)row*N + col] += v;
          } else if (EPI == 3){
            int n = row / 29, kr = row - n*29;
            ((float*)Cv)[((size_t)n*49 + c_res[kr])*128 + col] += v;
          } else if (EPI == 4){
            ((float*)Cv)[(size_t)row*N + col] = 1.f/(1.f + expf(-v));
          } else {
            float g = P0[(size_t)(row/49)*N + col];
            ((u16*)Cv)[(size_t)row*N + col] = f2bf(v*g);
          }
        }
      }
    }
  }
}

// ---------------- node init ----------------
__global__ __launch_bounds__(128) void k_init(const float* __restrict__ pos, const float* __restrict__ table,
                                              const float* __restrict__ Yb, const float* __restrict__ radd,
                                              const int* __restrict__ rowptr, const int* __restrict__ eid,
                                              float* __restrict__ x){
  int n = blockIdx.x;
  int c = threadIdx.x;
  const float DLO = -3.26267f;
  const float DRG = (float)(3.295396 - (-3.26267));
  float p0 = pos[n*3+0], p1 = pos[n*3+1], p2 = pos[n*3+2];
  int t0 = min(127, max(0, (int)rintf((p0 - DLO)/DRG*128.f - 0.5f)));
  int t1 = min(127, max(0, (int)rintf((p1 - DLO)/DRG*128.f - 0.5f)));
  int t2 = min(127, max(0, (int)rintf((p2 - DLO)/DRG*128.f - 0.5f)));
  float emb = table[t0*CD + c] + table[t1*CD + c] + table[t2*CD + c];
  __shared__ float Yl[49];
  __shared__ float rl[896];
  float acc[NCO];
  #pragma unroll
  for (int k = 0; k < NCO; k++) acc[k] = 0.f;
  int pA = rowptr[n], pB = rowptr[n+1];
  for (int p = pA; p < pB; p++){
    int e = eid[p];
    if (c < 49) Yl[c] = Yb[(size_t)e*49 + c];
    #pragma unroll
    for (int q = 0; q < 7; q++) rl[q*128 + c] = radd[(size_t)e*896 + q*128 + c];
    __syncthreads();
    #pragma unroll
    for (int k = 0; k < NCO; k++){
      acc[k] += Yl[k]*rl[deg_of(k)*128 + c];
    }
    __syncthreads();
  }
  size_t base = (size_t)n*NCO*CD;
  x[base + c] = emb + acc[0]*(1.f/3.f);
  #pragma unroll
  for (int k = 1; k < NCO; k++) x[base + k*CD + c] = acc[k]*(1.f/3.f);
}

// ---------------- degree-grouped RMS norm (full 49 rows, for FFN) ----------------
__global__ __launch_bounds__(128) void k_rmsnorm(const float* __restrict__ x, const float* __restrict__ w,
                                                 float* __restrict__ out){
  int n = blockIdx.x;
  int c = threadIdx.x;
  const float* xb = x + (size_t)n*NCO*CD;
  float vals[NCO];
  float ss[7] = {0,0,0,0,0,0,0};
  #pragma unroll
  for (int k = 0; k < NCO; k++){
    float v = xb[k*CD + c];
    vals[k] = v;
    ss[deg_of(k)] += v*v;
  }
  __shared__ float red[7][128];
  #pragma unroll
  for (int l = 0; l < 7; l++) red[l][c] = ss[l];
  __syncthreads();
  __shared__ float inv[7];
  if (c < 7){
    float s = 0.f;
    for (int i = 0; i < 128; i++) s += red[c][i];
    float ms = s / ((float)(2*c + 1)*128.f);
    inv[c] = 1.f / sqrtf(ms + 1e-6f);
  }
  __syncthreads();
  size_t base = (size_t)n*NCO*CD;
  #pragma unroll
  for (int k = 0; k < NCO; k++){
    int l = deg_of(k);
    out[base + k*CD + c] = vals[k]*inv[l]*w[l*CD + c];
  }
}

// ---------------- RMS norm writing restricted 29 rows directly ----------------
__global__ __launch_bounds__(128) void k_rmsnormR(const float* __restrict__ x, const float* __restrict__ w,
                                                  float* __restrict__ hr){
  int n = blockIdx.x;
  int c = threadIdx.x;
  const float* xb = x + (size_t)n*NCO*CD;
  float vals[NCO];
  float ss[7] = {0,0,0,0,0,0,0};
  #pragma unroll
  for (int k = 0; k < NCO; k++){
    float v = xb[k*CD + c];
    vals[k] = v;
    ss[deg_of(k)] += v*v;
  }
  __shared__ float red[7][128];
  #pragma unroll
  for (int l = 0; l < 7; l++) red[l][c] = ss[l];
  __syncthreads();
  __shared__ float inv[7];
  if (c < 7){
    float s = 0.f;
    for (int i = 0; i < 128; i++) s += red[c][i];
    float ms = s / ((float)(2*c + 1)*128.f);
    inv[c] = 1.f / sqrtf(ms + 1e-6f);
  }
  __syncthreads();
  size_t base = (size_t)n*NRr*CD;
  #pragma unroll
  for (int kr = 0; kr < NRr; kr++){
    int k = d_RES[kr];
    int l = deg_of(k);
    hr[base + kr*CD + c] = vals[k]*inv[l]*w[l*CD + c];
  }
}

// ---------------- attention small kernels ----------------
__global__ void k_logits(const float* __restrict__ XST, const float* __restrict__ rad,
                         const float* __restrict__ avec,
                         const int* __restrict__ src, const int* __restrict__ dst,
                         float* __restrict__ lg){
  int idx = blockIdx.x*blockDim.x + threadIdx.x;
  if (idx >= NE*8) return;
  int e = idx >> 3, hh = idx & 7;
  int s = src[e], t = dst[e];
  float acc = 0.f;
  #pragma unroll
  for (int dd = 0; dd < 16; dd++){
    int j = hh*16 + dd;
    float m = (XST[(size_t)s*NRr*256 + j] + XST[(size_t)t*NRr*256 + 128 + j]) * rad[(size_t)e*CD + j];
    acc += siluf(m)*avec[hh*16 + dd];
  }
  lg[idx] = acc;
}
__global__ void k_softmax(const float* __restrict__ lg, const int* __restrict__ rowptr,
                          const int* __restrict__ eid, float* __restrict__ mx, float* __restrict__ den){
  int idx = blockIdx.x*blockDim.x + threadIdx.x;
  if (idx >= NN*8) return;
  int n = idx >> 3, hh = idx & 7;
  int p0 = rowptr[n], p1 = rowptr[n+1];
  float m = -1e30f;
  for (int p = p0; p < p1; p++) m = fmaxf(m, lg[eid[p]*8 + hh]);
  float s = 0.f;
  for (int p = p0; p < p1; p++) s += expf(lg[eid[p]*8 + hh] - m);
  mx[idx] = m; den[idx] = s;
}
// aggregation with alpha computed in-register from lg/mx/den
__global__ __launch_bounds__(128) void k_agg(const float* __restrict__ V, const float* __restrict__ lg,
                                             const float* __restrict__ mx, const float* __restrict__ den,
                                             const int* __restrict__ rowptr, const int* __restrict__ eid,
                                             int e0, int e1, int first, float* __restrict__ agg){
  int n = blockIdx.x;
  int k = blockIdx.y;
  int c = threadIdx.x;
  size_t oidx = ((size_t)n*NRr + k)*CD + c;
  float s = first ? 0.f : agg[oidx];
  int hh = c >> 4;
  float m = mx[n*8 + hh];
  float inv = 1.f / fmaxf(den[n*8 + hh], 1e-9f);
  int p0 = rowptr[n], p1 = rowptr[n+1];
  for (int p = p0; p < p1; p++){
    int e = eid[p];
    if (e < e0 || e >= e1) continue;
    float a = expf(lg[e*8 + hh] - m) * inv;
    s += a*V[((size_t)(e - e0)*NRr + k)*CD + c];
  }
  agg[oidx] = s;
}

// ---------------- pooling ----------------
__global__ void k_pool(const float* __restrict__ orr, const int* __restrict__ gs, float* __restrict__ out){
  int i = blockIdx.x*blockDim.x + threadIdx.x;
  if (i >= NG*NCO*CD) return;
  int c = i & 127;
  int k = (i >> 7) % 49;
  int g = i / (49*128);
  int kr = c_rinv[k];
  float v = 0.f;
  if (kr >= 0){
    int a = gs[g], b = gs[g+1];
    float s = 0.f;
    for (int n = a; n < b; n++) s += orr[((size_t)n*29 + kr)*128 + c];
    int cnt = b - a;
    v = s / (float)(cnt > 0 ? cnt : 1);
  }
  out[i] = v;
}

extern "C" void kernel_launch(void* const* d_in, const int* in_sizes, int n_in,
                              void* d_out, int out_size, void* d_ws, size_t ws_size,
                              hipStream_t stream){
  const float* pos    = (const float*)d_in[0];
  const float* evec   = (const float*)d_in[1];
  const int*   eidx   = (const int*)  d_in[2];
  const int*   batch  = (const int*)  d_in[3];
  const float* table  = (const float*)d_in[4];
  const float* deg_w1 = (const float*)d_in[5];
  const float* deg_b1 = (const float*)d_in[6];
  const float* deg_w2 = (const float*)d_in[7];
  const float* deg_b2 = (const float*)d_in[8];
  const float* deg_w3 = (const float*)d_in[9];
  const float* attn_nw= (const float*)d_in[10];
  const float* w_src  = (const float*)d_in[11];
  const float* w_tgt  = (const float*)d_in[12];
  const float* rad_w1 = (const float*)d_in[13];
  const float* rad_b1 = (const float*)d_in[14];
  const float* rad_w2 = (const float*)d_in[15];
  const float* avec   = (const float*)d_in[16];
  const float* w_val  = (const float*)d_in[17];
  const float* w_proj = (const float*)d_in[18];
  const float* ffn_nw = (const float*)d_in[19];
  const float* ffn_w1 = (const float*)d_in[20];
  const float* ffn_w2 = (const float*)d_in[21];
  const float* fin_nw = (const float*)d_in[22];
  const float* lw_src = (const float*)d_in[23];
  const float* lw_tgt = (const float*)d_in[24];
  const float* lrad_w1= (const float*)d_in[25];
  const float* lrad_b1= (const float*)d_in[26];
  const float* lrad_w2= (const float*)d_in[27];
  const float* lavec  = (const float*)d_in[28];
  const float* lw_val = (const float*)d_in[29];
  const float* lw_proj= (const float*)d_in[30];

  const int* srcp = eidx;
  const int* dstp = eidx + NE;

  float* W = (float*)d_ws;
  size_t o = 0;
  float* X    = W + o; o += (size_t)NN*49*128;
  float* Hb   = W + o; o += (size_t)NN*49*128;   // also V chunks, latent proj out
  float* HR   = W + o; o += (size_t)NN*29*128;   // also agg; FFN hidden (bf16) start
  float* XSTb = W + o; o += (size_t)NN*29*256;   // XS|XT concat; also rad_deg, FFN hidden spill
  float* R1   = W + o; o += (size_t)NE*128;
  float* R2   = W + o; o += (size_t)NE*128;
  float* Yb   = W + o; o += (size_t)NE*49;
  float* DV   = W + o; o += (size_t)NE;
  float* LG   = W + o; o += (size_t)NE*8;
  float* MX   = W + o; o += (size_t)NN*8;
  float* DEN  = W + o; o += (size_t)NN*8;
  float* SG   = W + o; o += (size_t)NN*512;
  int* CNT = (int*)(W + o); o += NN;
  int* RP  = (int*)(W + o); o += NN + 1;
  int* EID = (int*)(W + o); o += NE;
  int* GS  = (int*)(W + o); o += NG + 1;
  int* CH  = (int*)(W + o); o += 4*NN;
  // bf16 transposed weights
  u16* WB = (u16*)(W + o);
  size_t wo = 0;
  u16* T_degw2 = WB + wo; wo += 16384;
  u16* T_degw3 = WB + wo; wo += 114688;
  u16* T_wst[3]; u16* T_wv[3]; u16* T_wp[3]; u16* T_rw2[3];
  for (int i = 0; i < 3; i++){ T_wst[i] = WB + wo; wo += 32768; }   // [256][128]: ws rows 0-127, wt rows 128-255
  for (int i = 0; i < 3; i++){ T_wv[i] = WB + wo; wo += 16384; }
  for (int i = 0; i < 3; i++){ T_wp[i] = WB + wo; wo += 16384; }
  for (int i = 0; i < 3; i++){ T_rw2[i] = WB + wo; wo += 16384; }
  u16* T_f1[2]; u16* T_f2[2];
  for (int i = 0; i < 2; i++){ T_f1[i] = WB + wo; wo += 65536; }
  for (int i = 0; i < 2; i++){ T_f2[i] = WB + wo; wo += 65536; }
  (void)ws_size; (void)in_sizes; (void)n_in; (void)out_size;

  float* RADD = XSTb;                             // E*896 = 11.0M <= XSTb (15.2M)
  float* VCH  = Hb;                               // ECHUNK*29*128 = 11.4M <= Hb (12.8M)
  float* AG   = HR;
  float* OR_  = Hb;                               // latent proj out
  u16*  F1B   = (u16*)HR;                         // 50176*512 u16 = 25.7M u16 <= HR+XSTb (45.6M u16)

  // ---- all weight casts in one launch ----
  {
    CastJobs J;
    int idx = 0, acc = 0;
    auto add = [&](const float* s, u16* d, int K, int N){
      J.src[idx] = s; J.dst[idx] = d; J.K[idx] = K; J.N[idx] = N; J.start[idx] = acc;
      acc += K*N; idx++;
    };
    add(deg_w2, T_degw2, 128, 128);
    add(deg_w3, T_degw3, 128, 896);
    for (int i = 0; i < 3; i++){
      add((i < 2) ? w_src  + (size_t)i*16384 : lw_src,  T_wst[i],          128, 128);
      add((i < 2) ? w_tgt  + (size_t)i*16384 : lw_tgt,  T_wst[i] + 16384,  128, 128);
      add((i < 2) ? w_val  + (size_t)i*16384 : lw_val,  T_wv[i], 128, 128);
      add((i < 2) ? w_proj + (size_t)i*16384 : lw_proj, T_wp[i], 128, 128);
      add((i < 2) ? rad_w2 + (size_t)i*16384 : lrad_w2, T_rw2[i], 128, 128);
    }
    for (int i = 0; i < 2; i++){
      add(ffn_w1 + (size_t)i*65536, T_f1[i], 128, 512);
      add(ffn_w2 + (size_t)i*65536, T_f2[i], 512, 128);
    }
    J.start[idx] = acc; J.total = acc;
    k_castall<<<(acc + 255)/256, 256, 0, stream>>>(J);
  }

  // CSR + groups
  k_hist4<<<1, 1024, 0, stream>>>(dstp, CNT, CH);
  k_scan2<<<1, 1024, 0, stream>>>(CNT, RP);
  k_fillw4<<<NN, 256, 0, stream>>>(dstp, RP, CH, EID);
  k_gstart<<<1, 32, 0, stream>>>(batch, GS);

  // geometry
  k_geom<<<48, 256, 0, stream>>>(evec, Yb, DV);

  // degree embedding MLP: 600->128 (silu) -> 128 (silu) -> 896
  k_rad1<<<NE, 128, 0, stream>>>(DV, deg_w1, deg_b1, R1);
  k_mgemm<0,1,2><<<dim3(1, NE/64), 256, 0, stream>>>(R1, T_degw2, deg_b2, R2, NE, 128, 128, 128,
                                                     nullptr, nullptr, nullptr, 0);
  k_mgemm<0,0,2><<<dim3(7, NE/64), 256, 0, stream>>>(R2, T_degw3, nullptr, RADD, NE, 896, 128, 128,
                                                     nullptr, nullptr, nullptr, 0);
  k_init<<<NN, 128, 0, stream>>>(pos, table, Yb, RADD, RP, EID, X);

  for (int i = 0; i < 3; i++){
    const float* nw  = (i < 2) ? attn_nw + (size_t)i*896   : fin_nw;
    const float* rw1 = (i < 2) ? rad_w1 + (size_t)i*76800 : lrad_w1;
    const float* rb1 = (i < 2) ? rad_b1 + (size_t)i*128   : lrad_b1;
    const float* av  = (i < 2) ? avec   + (size_t)i*128   : lavec;

    k_rmsnormR<<<NN, 128, 0, stream>>>(X, nw, HR);
    // combined XS|XT projection: one pass over HR, N=256
    k_mgemm<0,0,4><<<dim3(1, NN*NRr/64), 256, 0, stream>>>(HR, T_wst[i], nullptr, XSTb, NN*NRr, 256, 128, 128,
                                                           nullptr, nullptr, nullptr, 0);
    k_rad1<<<NE, 128, 0, stream>>>(DV, rw1, rb1, R1);
    k_mgemm<0,0,2><<<dim3(1, NE/64), 256, 0, stream>>>(R1, T_rw2[i], nullptr, R2, NE, 128, 128, 128,
                                                       nullptr, nullptr, nullptr, 0);
    k_logits<<<(NE*8 + 255)/256, 256, 0, stream>>>(XSTb, R2, av, srcp, dstp, LG);
    k_softmax<<<(NN*8 + 255)/256, 256, 0, stream>>>(LG, RP, EID, MX, DEN);
    for (int ch = 0; ch < NE/ECHUNK; ch++){
      int e0 = ch*ECHUNK;
      k_mgemm<1,0,2><<<dim3(1, ECHUNK*NRr/64), 256, 0, stream>>>(R2, T_wv[i], nullptr, VCH,
                                                                 ECHUNK*NRr, 128, 128, 128,
                                                                 XSTb, srcp, dstp, e0);
      k_agg<<<dim3(NN, NRr), 128, 0, stream>>>(VCH, LG, MX, DEN, RP, EID, e0, e0 + ECHUNK, ch == 0, AG);
    }
    if (i < 2){
      // projection with fused scatter-accumulate into X
      k_mgemm<0,3,2><<<dim3(1, NN*NRr/64), 256, 0, stream>>>(AG, T_wp[i], nullptr, X, NN*NRr, 128, 128, 128,
                                                             nullptr, nullptr, nullptr, 0);
      // FFN: h_gated[n,k,:] = (x@w1)[n,k,:] * sigmoid((x@w1)[n,0,:])  [silu(s)=s*sigmoid(s)]
      k_rmsnorm<<<NN, 128, 0, stream>>>(X, ffn_nw + (size_t)i*896, Hb);
      k_mgemm<0,4,4><<<dim3(2, NN/64), 256, 0, stream>>>(Hb, T_f1[i], nullptr, SG, NN, 512, 128, NCO*CD,
                                                         nullptr, nullptr, nullptr, 0);
      for (int half = 0; half < 2; half++){
        int n0 = half*(NN/2);
        int Mh = (NN/2)*NCO;   // 50176
        k_mgemm<0,5,4><<<dim3(2, Mh/64), 256, 0, stream>>>(Hb + (size_t)n0*NCO*CD, T_f1[i], nullptr, F1B,
                                                           Mh, 512, 128, 128,
                                                           SG + (size_t)n0*512, nullptr, nullptr, 0);
        k_mgemm<2,2,2><<<dim3(1, Mh/64), 256, 0, stream>>>(F1B, T_f2[i], nullptr, X + (size_t)n0*NCO*CD,
                                                           Mh, 128, 512, 512,
                                                           nullptr, nullptr, nullptr, 0);
      }
    } else {
      k_mgemm<0,0,2><<<dim3(1, NN*NRr/64), 256, 0, stream>>>(AG, T_wp[i], nullptr, OR_, NN*NRr, 128, 128, 128,
                                                             nullptr, nullptr, nullptr, 0);
      k_pool<<<(NG*NCO*CD + 255)/256, 256, 0, stream>>>(OR_, GS, (float*)d_out);
    }
  }
}

// Round 8
// 1125.705 us; speedup vs baseline: 4.5303x; 1.2741x over previous
//
#include <hip/hip_runtime.h>
#include <math.h>

#define NN 2048
#define NE 12288
#define NCO 49
#define NRr 29
#define CD 128
#define NG 16
#define NJOBS 21

typedef unsigned short u16;
typedef short bhalf8 __attribute__((ext_vector_type(8)));
typedef float fvec4 __attribute__((ext_vector_type(4)));

// RESTRICT: indices k (0..48) with |m|<=2.
__constant__ int c_res[29] = {0,1,2,3,4,5,6,7,8,10,11,12,13,14,18,19,20,21,22,28,29,30,31,32,40,41,42,43,44};
__constant__ int c_rinv[49] = {0,1,2,3,4,5,6,7,8,-1,9,10,11,12,13,-1,-1,-1,14,15,16,17,18,-1,-1,-1,-1,-1,19,20,21,22,23,-1,-1,-1,-1,-1,-1,-1,24,25,26,27,28,-1,-1,-1,-1};
__device__ constexpr int d_RES[29] = {0,1,2,3,4,5,6,7,8,10,11,12,13,14,18,19,20,21,22,28,29,30,31,32,40,41,42,43,44};

__device__ __forceinline__ constexpr int deg_of(int k){
  return (k<1)?0:(k<4)?1:(k<9)?2:(k<16)?3:(k<25)?4:(k<36)?5:6;
}
__device__ __forceinline__ float siluf(float x){ return x / (1.f + expf(-x)); }
__device__ __forceinline__ u16 f2bf(float f){
  unsigned int u = __float_as_uint(f);
  unsigned int r = (u + 0x7FFFu + ((u >> 16) & 1u)) >> 16;
  return (u16)r;
}
__device__ __forceinline__ float bf2f(u16 b){
  return __uint_as_float(((unsigned int)b) << 16);
}
__device__ __forceinline__ unsigned int pk(u16 lo, u16 hi){ return (unsigned int)lo | ((unsigned int)hi << 16); }

// ---------------- CSR build (deterministic, parallel) ----------------
__global__ __launch_bounds__(1024) void k_hist4(const int* __restrict__ dst, int* __restrict__ cnt,
                                                int* __restrict__ CH){
  __shared__ int h[4*NN];
  for (int i = threadIdx.x; i < 4*NN; i += 1024) h[i] = 0;
  __syncthreads();
  const int QE = NE/4;
  for (int e = threadIdx.x; e < NE; e += 1024){
    int q = e / QE;
    atomicAdd(&h[q*NN + dst[e]], 1);
  }
  __syncthreads();
  for (int n = threadIdx.x; n < NN; n += 1024){
    int s = 0;
    #pragma unroll
    for (int q = 0; q < 4; q++){ int v = h[q*NN + n]; CH[q*NN + n] = v; s += v; }
    cnt[n] = s;
  }
}
__global__ __launch_bounds__(1024) void k_scan2(const int* __restrict__ cnt, int* __restrict__ rowptr){
  __shared__ int a[NN], b[NN];
  int t = threadIdx.x;
  for (int i = t; i < NN; i += 1024) a[i] = cnt[i];
  __syncthreads();
  int* pin = a; int* pout = b;
  for (int off = 1; off < NN; off <<= 1){
    for (int i = t; i < NN; i += 1024)
      pout[i] = pin[i] + ((i >= off) ? pin[i - off] : 0);
    __syncthreads();
    int* tmp = pin; pin = pout; pout = tmp;
  }
  for (int i = t; i < NN; i += 1024) rowptr[i + 1] = pin[i];
  if (t == 0) rowptr[0] = 0;
}
__global__ __launch_bounds__(256) void k_fillw4(const int* __restrict__ dst, const int* __restrict__ rowptr,
                                                const int* __restrict__ CH, int* __restrict__ eid){
  int q = threadIdx.x >> 6, lane = threadIdx.x & 63;
  int n = blockIdx.x;
  int base = rowptr[n];
  for (int qq = 0; qq < q; qq++) base += CH[qq*NN + n];
  const int QE = NE/4;
  for (int e0 = q*QE; e0 < (q+1)*QE; e0 += 64){
    int e = e0 + lane;
    bool m = (dst[e] == n);
    unsigned long long mask = __ballot(m);
    if (m) eid[base + __popcll(mask & ((1ull << lane) - 1ull))] = e;
    base += __popcll(mask);
  }
}
__global__ void k_gstart(const int* __restrict__ batch, int* __restrict__ gs){
  int g = threadIdx.x;
  if (g > NG) return;
  int lo = 0, hi = NN;
  while (lo < hi){ int mid = (lo + hi) >> 1; if (batch[mid] < g) lo = mid + 1; else hi = mid; }
  gs[g] = lo;
}

// ---------------- all weight casts in one launch: [K][N] f32 -> [N][K] bf16 ----------------
struct CastJobs {
  const float* src[NJOBS];
  u16* dst[NJOBS];
  int K[NJOBS], N[NJOBS];
  int start[NJOBS + 1];
  int total;
};
__global__ void k_castall(CastJobs J){
  int i = blockIdx.x*blockDim.x + threadIdx.x;
  if (i >= J.total) return;
  int j = 0;
  while (i >= J.start[j + 1]) j++;
  int local = i - J.start[j];
  int K = J.K[j], N = J.N[j];
  int n = local / K, k = local - n*K;
  J.dst[j][local] = f2bf(J.src[j][(size_t)k*N + n]);
}

// ---------------- geometry ----------------
__global__ void k_geom(const float* __restrict__ ev, float* __restrict__ Y, float* __restrict__ dv){
  int e = blockIdx.x*blockDim.x + threadIdx.x;
  if (e >= NE) return;
  float x = ev[e*3+0], y = ev[e*3+1], z = ev[e*3+2];
  float r = sqrtf(x*x + y*y + z*z);
  dv[e] = r;
  float rn = fmaxf(r, 1e-8f);
  float ux = x/rn, uy = y/rn, uz = z/rn;
  float ct = fminf(fmaxf(uz, -1.f), 1.f);
  float st = sqrtf(fminf(fmaxf(1.f - ct*ct, 1e-12f), 1.f));
  float phi = atan2f(uy, ux);
  float P[7][7];
  P[0][0] = 1.f;
  #pragma unroll
  for (int m = 1; m <= 6; m++) P[m][m] = -(2.f*m - 1.f)*st*P[m-1][m-1];
  #pragma unroll
  for (int m = 0; m <= 5; m++) P[m+1][m] = (2.f*m + 1.f)*ct*P[m][m];
  #pragma unroll
  for (int m = 0; m <= 6; m++){
    #pragma unroll
    for (int l = m+2; l <= 6; l++)
      P[l][m] = ((2.f*l - 1.f)*ct*P[l-1][m] - (float)(l+m-1)*P[l-2][m]) / (float)(l-m);
  }
  float cmv[7], smv[7];
  #pragma unroll
  for (int m = 0; m <= 6; m++){ cmv[m] = cosf((float)m*phi); smv[m] = sinf((float)m*phi); }
  const double FOURPI = 12.566370614359172;
  int k = 0;
  #pragma unroll
  for (int l = 0; l <= 6; l++){
    #pragma unroll
    for (int mm = -l; mm <= l; mm++){
      int am = mm < 0 ? -mm : mm;
      double ratio = 1.0;
      for (int i = l-am+1; i <= l+am; i++) ratio /= (double)i;
      double nrm = sqrt((2.0*l + 1.0)/FOURPI*ratio);
      float v;
      if (mm == 0)      v = (float)nrm * P[l][0];
      else if (mm > 0)  v = (float)(1.4142135623730951*nrm) * P[l][am] * cmv[am];
      else              v = (float)(1.4142135623730951*nrm) * P[l][am] * smv[am];
      Y[(size_t)e*49 + k] = v; k++;
    }
  }
}

// ------------- layer-1 of radial MLPs (windowed gaussian, exact) -------------
__global__ __launch_bounds__(128) void k_rad1(const float* __restrict__ dv, const float* __restrict__ Wm,
                                              const float* __restrict__ bias, float* __restrict__ out){
  int e = blockIdx.x;
  int j = threadIdx.x;
  float d = dv[e];
  const float STEPF = (float)(5.0/599.0);
  const double step_d = (double)STEPF;
  const float GC = (float)(-0.5/((2.0*step_d)*(2.0*step_d)));
  __shared__ float g[64];
  int bc = (int)rintf(d / STEPF);
  int b0 = bc - 32;
  if (j < 64){
    int b = b0 + j;
    float gg = 0.f;
    if (b >= 0 && b < 600){
      float off = (float)((double)b * (5.0/599.0));
      float t = d - off;
      gg = expf(GC*t*t);
    }
    g[j] = gg;
  }
  __syncthreads();
  float acc = bias ? bias[j] : 0.f;
  #pragma unroll 8
  for (int i = 0; i < 64; i++){
    int b = b0 + i;
    if (b >= 0 && b < 600) acc += g[i]*Wm[b*CD + j];
  }
  out[(size_t)e*CD + j] = siluf(acc);
}

// ---------------- MFMA bf16 GEMM with NT column-tiles per block ----------------
// AMODE: 0 = f32 A (runtime lda); 2 = bf16 A (runtime lda).
// EPI:   0 store(+bias); 1 silu(+bias); 2 accumulate; 3 scatter-accum into X;
//        4 sigmoid store; 5 gate-mul (P0=SG) then bf16 store; 6 bf16 store.
template<int AMODE, int EPI, int NT>
__global__ __launch_bounds__(256) void k_mgemm(
    const void* __restrict__ Av, const u16* __restrict__ Bt,
    const float* __restrict__ bias, void* __restrict__ Cv,
    int M, int N, int K, int lda,
    const float* __restrict__ P0)
{
  __shared__ __align__(16) u16 Asl[64*64];
  __shared__ __align__(16) u16 Bsl[NT][64*64];
  int tid = threadIdx.x;
  int bm = blockIdx.y*64;
  int bn0 = blockIdx.x*NT*64;
  int wid = tid >> 6, lane = tid & 63;
  int wr = wid >> 1, wc = wid & 1;
  int lr = lane & 15, lk = lane >> 4;
  fvec4 acc[NT][2][2] = {};
  for (int k0 = 0; k0 < K; k0 += 64){
    #pragma unroll
    for (int h = 0; h < 2; h++){
      int lin = tid + h*256;          // 0..511: 64 rows x 8 k-groups
      int row = lin >> 3, kg = lin & 7;
      uint4 q;
      if (AMODE == 2){
        const u16* ap = (const u16*)Av + (size_t)(bm + row)*lda + k0 + kg*8;
        q = *(const uint4*)ap;
      } else {
        const float* ap = (const float*)Av + (size_t)(bm + row)*lda + k0 + kg*8;
        float v[8];
        #pragma unroll
        for (int j = 0; j < 8; j++) v[j] = ap[j];
        q.x = pk(f2bf(v[0]), f2bf(v[1]));
        q.y = pk(f2bf(v[2]), f2bf(v[3]));
        q.z = pk(f2bf(v[4]), f2bf(v[5]));
        q.w = pk(f2bf(v[6]), f2bf(v[7]));
      }
      *(uint4*)&Asl[row*64 + ((kg*8) ^ ((row & 7)*8))] = q;
    }
    #pragma unroll
    for (int t = 0; t < NT; t++){
      #pragma unroll
      for (int h = 0; h < 2; h++){
        int lin = tid + h*256;
        int row = lin >> 3, kg = lin & 7;
        const u16* bp = Bt + (size_t)(bn0 + t*64 + row)*K + k0 + kg*8;
        *(uint4*)&Bsl[t][row*64 + ((kg*8) ^ ((row & 7)*8))] = *(const uint4*)bp;
      }
    }
    __syncthreads();
    #pragma unroll
    for (int ks = 0; ks < 2; ks++){
      int kg = ks*4 + lk;
      bhalf8 af[2];
      #pragma unroll
      for (int mi = 0; mi < 2; mi++){
        int ar = wr*32 + mi*16 + lr;
        af[mi] = *(const bhalf8*)&Asl[ar*64 + ((kg*8) ^ ((ar & 7)*8))];
      }
      #pragma unroll
      for (int t = 0; t < NT; t++){
        bhalf8 bfr[2];
        #pragma unroll
        for (int ni = 0; ni < 2; ni++){
          int br = wc*32 + ni*16 + lr;
          bfr[ni] = *(const bhalf8*)&Bsl[t][br*64 + ((kg*8) ^ ((br & 7)*8))];
        }
        #pragma unroll
        for (int mi = 0; mi < 2; mi++)
          #pragma unroll
          for (int ni = 0; ni < 2; ni++)
            acc[t][mi][ni] = __builtin_amdgcn_mfma_f32_16x16x32_bf16(af[mi], bfr[ni], acc[t][mi][ni], 0, 0, 0);
      }
    }
    __syncthreads();
  }
  #pragma unroll
  for (int t = 0; t < NT; t++){
    #pragma unroll
    for (int mi = 0; mi < 2; mi++){
      #pragma unroll
      for (int ni = 0; ni < 2; ni++){
        #pragma unroll
        for (int j = 0; j < 4; j++){
          int row = bm + wr*32 + mi*16 + lk*4 + j;
          int col = bn0 + t*64 + wc*32 + ni*16 + lr;
          float v = acc[t][mi][ni][j];
          if (EPI == 0){
            if (bias) v += bias[col];
            ((float*)Cv)[(size_t)row*N + col] = v;
          } else if (EPI == 1){
            if (bias) v += bias[col];
            ((float*)Cv)[(size_t)row*N + col] = siluf(v);
          } else if (EPI == 2){
            ((float*)Cv)[(size_t)row*N + col] += v;
          } else if (EPI == 3){
            int n = row / 29, kr = row - n*29;
            ((float*)Cv)[((size_t)n*49 + c_res[kr])*128 + col] += v;
          } else if (EPI == 4){
            ((float*)Cv)[(size_t)row*N + col] = 1.f/(1.f + expf(-v));
          } else if (EPI == 5){
            float g = P0[(size_t)(row/49)*N + col];
            ((u16*)Cv)[(size_t)row*N + col] = f2bf(v*g);
          } else {
            ((u16*)Cv)[(size_t)row*N + col] = f2bf(v);
          }
        }
      }
    }
  }
}

// ---------------- fused V-compute + alpha-weighted aggregation (per node) ----------------
// XST: [NN][29][256] bf16 (xs | xt). rad: [NE][128] f32. wvT: [128][128] bf16 ([col][k]).
// agg[n][kq][c] = sum_e alpha[e, c>>4] * ((xs[src_e,kq,:]+xt[n,kq,:]) .* rad[e,:]) @ wv [:,c]
__global__ __launch_bounds__(256) void k_vagg(
    const u16* __restrict__ XST, const float* __restrict__ rad, const u16* __restrict__ wvT,
    const float* __restrict__ lg, const float* __restrict__ mx, const float* __restrict__ den,
    const int* __restrict__ rowptr, const int* __restrict__ eid, const int* __restrict__ src,
    float* __restrict__ agg)
{
  __shared__ __align__(16) u16 Bs[128*128];   // wvT swizzled (32 KB); reused as f32 reduce buf at end
  __shared__ __align__(16) u16 As[64*128];    // msg tile swizzled (16 KB)
  __shared__ __align__(16) u16 XTl[29*128];   // this node's xt rows (7.25 KB)
  int n = blockIdx.x;
  int tid = threadIdx.x;
  int w = tid >> 6, lane = tid & 63;
  int lr = lane & 15, lk = lane >> 4;
  // stage wvT swizzled: 128 rows x 16 kgroups
  for (int g = tid; g < 128*16; g += 256){
    int col = g >> 4, kg = g & 15;
    *(uint4*)&Bs[col*128 + ((kg*8) ^ ((col & 7)*16))] = *(const uint4*)&wvT[(size_t)col*128 + kg*8];
  }
  // stage xt rows (linear)
  for (int g = tid; g < 29*16; g += 256){
    int kq = g >> 4, kg = g & 15;
    *(uint4*)&XTl[kq*128 + kg*8] = *(const uint4*)&XST[((size_t)n*29 + kq)*256 + 128 + kg*8];
  }
  int p0 = rowptr[n], p1 = rowptr[n+1];
  int deg = p1 - p0;
  int npass = (deg + 1) >> 1;
  float acc_sum[4][2][4];
  #pragma unroll
  for (int m = 0; m < 4; m++)
    #pragma unroll
    for (int nt = 0; nt < 2; nt++)
      #pragma unroll
      for (int j = 0; j < 4; j++) acc_sum[m][nt][j] = 0.f;
  float mh[2], invd[2];
  #pragma unroll
  for (int nt = 0; nt < 2; nt++){
    int h = w*2 + nt;
    mh[nt] = mx[n*8 + h];
    invd[nt] = 1.f / fmaxf(den[n*8 + h], 1e-9f);
  }
  for (int ps = 0; ps < npass; ps++){
    int e0v = eid[p0 + ps*2];
    int e1v = (ps*2 + 1 < deg) ? eid[p0 + ps*2 + 1] : -1;
    int s0 = src[e0v];
    int s1 = (e1v >= 0) ? src[e1v] : 0;
    __syncthreads();   // prev MFMA done (ps>0) / initial staging done (ps==0)
    // stage A: 64 rows x 16 kgroups
    for (int g = tid; g < 1024; g += 256){
      int row = g >> 4, kg = g & 15;
      uint4 q = {0u,0u,0u,0u};
      if (row < 58){
        int pe = (row >= 29);
        int e = pe ? e1v : e0v;
        if (e >= 0){
          int kq = row - 29*pe;
          int s = pe ? s1 : s0;
          uint4 xs8 = *(const uint4*)&XST[((size_t)s*29 + kq)*256 + kg*8];
          uint4 xt8 = *(const uint4*)&XTl[kq*128 + kg*8];
          const float* rd = &rad[(size_t)e*128 + kg*8];
          const u16* xsp = (const u16*)&xs8;
          const u16* xtp = (const u16*)&xt8;
          u16 ov[8];
          #pragma unroll
          for (int j = 0; j < 8; j++)
            ov[j] = f2bf((bf2f(xsp[j]) + bf2f(xtp[j])) * rd[j]);
          q.x = pk(ov[0], ov[1]); q.y = pk(ov[2], ov[3]);
          q.z = pk(ov[4], ov[5]); q.w = pk(ov[6], ov[7]);
        }
      }
      *(uint4*)&As[row*128 + ((kg*8) ^ ((row & 7)*16))] = q;
    }
    __syncthreads();
    // MFMA 64x32 per wave (cols 32w..32w+32), K=128
    fvec4 pacc[4][2] = {};
    #pragma unroll
    for (int kk = 0; kk < 4; kk++){
      int kg = kk*4 + lk;
      bhalf8 af[4];
      #pragma unroll
      for (int m = 0; m < 4; m++){
        int ar = m*16 + lr;
        af[m] = *(const bhalf8*)&As[ar*128 + ((kg*8) ^ ((ar & 7)*16))];
      }
      #pragma unroll
      for (int nt = 0; nt < 2; nt++){
        int col = w*32 + nt*16 + lr;
        bhalf8 bfr = *(const bhalf8*)&Bs[col*128 + ((kg*8) ^ ((col & 7)*16))];
        #pragma unroll
        for (int m = 0; m < 4; m++)
          pacc[m][nt] = __builtin_amdgcn_mfma_f32_16x16x32_bf16(af[m], bfr, pacc[m][nt], 0, 0, 0);
      }
    }
    // alpha-scale and accumulate (register, deterministic order)
    #pragma unroll
    for (int m = 0; m < 4; m++){
      #pragma unroll
      for (int j = 0; j < 4; j++){
        int row = m*16 + lk*4 + j;
        if (row < 58){
          int pe = (row >= 29);
          int e = pe ? e1v : e0v;
          if (e >= 0){
            #pragma unroll
            for (int nt = 0; nt < 2; nt++){
              int h = w*2 + nt;
              float a = expf(lg[e*8 + h] - mh[nt]) * invd[nt];
              acc_sum[m][nt][j] += a * pacc[m][nt][j];
            }
          }
        }
      }
    }
  }
  __syncthreads();
  // final reduce pe=0 + pe=1 via LDS (reuse Bs as f32 [64][128])
  float* Lf = (float*)Bs;
  #pragma unroll
  for (int m = 0; m < 4; m++)
    #pragma unroll
    for (int nt = 0; nt < 2; nt++)
      #pragma unroll
      for (int j = 0; j < 4; j++){
        int row = m*16 + lk*4 + j;
        int col = w*32 + nt*16 + lr;
        Lf[row*128 + col] = acc_sum[m][nt][j];
      }
  __syncthreads();
  for (int g = tid; g < 29*128; g += 256){
    int kq = g >> 7, c = g & 127;
    agg[((size_t)n*29 + kq)*128 + c] = Lf[kq*128 + c] + Lf[(kq + 29)*128 + c];
  }
}

// ---------------- node init ----------------
__global__ __launch_bounds__(128) void k_init(const float* __restrict__ pos, const float* __restrict__ table,
                                              const float* __restrict__ Yb, const float* __restrict__ radd,
                                              const int* __restrict__ rowptr, const int* __restrict__ eid,
                                              float* __restrict__ x){
  int n = blockIdx.x;
  int c = threadIdx.x;
  const float DLO = -3.26267f;
  const float DRG = (float)(3.295396 - (-3.26267));
  float p0 = pos[n*3+0], p1 = pos[n*3+1], p2 = pos[n*3+2];
  int t0 = min(127, max(0, (int)rintf((p0 - DLO)/DRG*128.f - 0.5f)));
  int t1 = min(127, max(0, (int)rintf((p1 - DLO)/DRG*128.f - 0.5f)));
  int t2 = min(127, max(0, (int)rintf((p2 - DLO)/DRG*128.f - 0.5f)));
  float emb = table[t0*CD + c] + table[t1*CD + c] + table[t2*CD + c];
  __shared__ float Yl[49];
  __shared__ float rl[896];
  float acc[NCO];
  #pragma unroll
  for (int k = 0; k < NCO; k++) acc[k] = 0.f;
  int pA = rowptr[n], pB = rowptr[n+1];
  for (int p = pA; p < pB; p++){
    int e = eid[p];
    if (c < 49) Yl[c] = Yb[(size_t)e*49 + c];
    #pragma unroll
    for (int q = 0; q < 7; q++) rl[q*128 + c] = radd[(size_t)e*896 + q*128 + c];
    __syncthreads();
    #pragma unroll
    for (int k = 0; k < NCO; k++){
      acc[k] += Yl[k]*rl[deg_of(k)*128 + c];
    }
    __syncthreads();
  }
  size_t base = (size_t)n*NCO*CD;
  x[base + c] = emb + acc[0]*(1.f/3.f);
  #pragma unroll
  for (int k = 1; k < NCO; k++) x[base + k*CD + c] = acc[k]*(1.f/3.f);
}

// ---------------- degree-grouped RMS norm (full 49 rows, for FFN) ----------------
__global__ __launch_bounds__(128) void k_rmsnorm(const float* __restrict__ x, const float* __restrict__ w,
                                                 float* __restrict__ out){
  int n = blockIdx.x;
  int c = threadIdx.x;
  const float* xb = x + (size_t)n*NCO*CD;
  float vals[NCO];
  float ss[7] = {0,0,0,0,0,0,0};
  #pragma unroll
  for (int k = 0; k < NCO; k++){
    float v = xb[k*CD + c];
    vals[k] = v;
    ss[deg_of(k)] += v*v;
  }
  __shared__ float red[7][128];
  #pragma unroll
  for (int l = 0; l < 7; l++) red[l][c] = ss[l];
  __syncthreads();
  __shared__ float inv[7];
  if (c < 7){
    float s = 0.f;
    for (int i = 0; i < 128; i++) s += red[c][i];
    float ms = s / ((float)(2*c + 1)*128.f);
    inv[c] = 1.f / sqrtf(ms + 1e-6f);
  }
  __syncthreads();
  size_t base = (size_t)n*NCO*CD;
  #pragma unroll
  for (int k = 0; k < NCO; k++){
    int l = deg_of(k);
    out[base + k*CD + c] = vals[k]*inv[l]*w[l*CD + c];
  }
}

// ---------------- RMS norm writing restricted 29 rows directly ----------------
__global__ __launch_bounds__(128) void k_rmsnormR(const float* __restrict__ x, const float* __restrict__ w,
                                                  float* __restrict__ hr){
  int n = blockIdx.x;
  int c = threadIdx.x;
  const float* xb = x + (size_t)n*NCO*CD;
  float vals[NCO];
  float ss[7] = {0,0,0,0,0,0,0};
  #pragma unroll
  for (int k = 0; k < NCO; k++){
    float v = xb[k*CD + c];
    vals[k] = v;
    ss[deg_of(k)] += v*v;
  }
  __shared__ float red[7][128];
  #pragma unroll
  for (int l = 0; l < 7; l++) red[l][c] = ss[l];
  __syncthreads();
  __shared__ float inv[7];
  if (c < 7){
    float s = 0.f;
    for (int i = 0; i < 128; i++) s += red[c][i];
    float ms = s / ((float)(2*c + 1)*128.f);
    inv[c] = 1.f / sqrtf(ms + 1e-6f);
  }
  __syncthreads();
  size_t base = (size_t)n*NRr*CD;
  #pragma unroll
  for (int kr = 0; kr < NRr; kr++){
    int k = d_RES[kr];
    int l = deg_of(k);
    hr[base + kr*CD + c] = vals[k]*inv[l]*w[l*CD + c];
  }
}

// ---------------- attention small kernels ----------------
__global__ void k_logits(const u16* __restrict__ XST, const float* __restrict__ rad,
                         const float* __restrict__ avec,
                         const int* __restrict__ src, const int* __restrict__ dst,
                         float* __restrict__ lg){
  int idx = blockIdx.x*blockDim.x + threadIdx.x;
  if (idx >= NE*8) return;
  int e = idx >> 3, hh = idx & 7;
  int s = src[e], t = dst[e];
  float acc = 0.f;
  #pragma unroll
  for (int dd = 0; dd < 16; dd++){
    int j = hh*16 + dd;
    float m = (bf2f(XST[(size_t)s*NRr*256 + j]) + bf2f(XST[(size_t)t*NRr*256 + 128 + j])) * rad[(size_t)e*CD + j];
    acc += siluf(m)*avec[hh*16 + dd];
  }
  lg[idx] = acc;
}
__global__ void k_softmax(const float* __restrict__ lg, const int* __restrict__ rowptr,
                          const int* __restrict__ eid, float* __restrict__ mx, float* __restrict__ den){
  int idx = blockIdx.x*blockDim.x + threadIdx.x;
  if (idx >= NN*8) return;
  int n = idx >> 3, hh = idx & 7;
  int p0 = rowptr[n], p1 = rowptr[n+1];
  float m = -1e30f;
  for (int p = p0; p < p1; p++) m = fmaxf(m, lg[eid[p]*8 + hh]);
  float s = 0.f;
  for (int p = p0; p < p1; p++) s += expf(lg[eid[p]*8 + hh] - m);
  mx[idx] = m; den[idx] = s;
}

// ---------------- pooling ----------------
__global__ void k_pool(const float* __restrict__ orr, const int* __restrict__ gs, float* __restrict__ out){
  int i = blockIdx.x*blockDim.x + threadIdx.x;
  if (i >= NG*NCO*CD) return;
  int c = i & 127;
  int k = (i >> 7) % 49;
  int g = i / (49*128);
  int kr = c_rinv[k];
  float v = 0.f;
  if (kr >= 0){
    int a = gs[g], b = gs[g+1];
    float s = 0.f;
    for (int n = a; n < b; n++) s += orr[((size_t)n*29 + kr)*128 + c];
    int cnt = b - a;
    v = s / (float)(cnt > 0 ? cnt : 1);
  }
  out[i] = v;
}

extern "C" void kernel_launch(void* const* d_in, const int* in_sizes, int n_in,
                              void* d_out, int out_size, void* d_ws, size_t ws_size,
                              hipStream_t stream){
  const float* pos    = (const float*)d_in[0];
  const float* evec   = (const float*)d_in[1];
  const int*   eidx   = (const int*)  d_in[2];
  const int*   batch  = (const int*)  d_in[3];
  const float* table  = (const float*)d_in[4];
  const float* deg_w1 = (const float*)d_in[5];
  const float* deg_b1 = (const float*)d_in[6];
  const float* deg_w2 = (const float*)d_in[7];
  const float* deg_b2 = (const float*)d_in[8];
  const float* deg_w3 = (const float*)d_in[9];
  const float* attn_nw= (const float*)d_in[10];
  const float* w_src  = (const float*)d_in[11];
  const float* w_tgt  = (const float*)d_in[12];
  const float* rad_w1 = (const float*)d_in[13];
  const float* rad_b1 = (const float*)d_in[14];
  const float* rad_w2 = (const float*)d_in[15];
  const float* avec   = (const float*)d_in[16];
  const float* w_val  = (const float*)d_in[17];
  const float* w_proj = (const float*)d_in[18];
  const float* ffn_nw = (const float*)d_in[19];
  const float* ffn_w1 = (const float*)d_in[20];
  const float* ffn_w2 = (const float*)d_in[21];
  const float* fin_nw = (const float*)d_in[22];
  const float* lw_src = (const float*)d_in[23];
  const float* lw_tgt = (const float*)d_in[24];
  const float* lrad_w1= (const float*)d_in[25];
  const float* lrad_b1= (const float*)d_in[26];
  const float* lrad_w2= (const float*)d_in[27];
  const float* lavec  = (const float*)d_in[28];
  const float* lw_val = (const float*)d_in[29];
  const float* lw_proj= (const float*)d_in[30];

  const int* srcp = eidx;
  const int* dstp = eidx + NE;

  float* W = (float*)d_ws;
  size_t o = 0;
  float* X    = W + o; o += (size_t)NN*49*128;
  float* Hb   = W + o; o += (size_t)NN*49*128;   // also RADD, latent proj out, FFN rmsnorm out
  float* HR   = W + o; o += (size_t)NN*29*128;   // rmsnormR out, AG, F1B start
  float* XSTf = W + o; o += (size_t)NN*29*256/2; // XST bf16 region (u16), F1B spill
  float* R1   = W + o; o += (size_t)NE*128;
  float* R2   = W + o; o += (size_t)NE*128;
  float* Yb   = W + o; o += (size_t)NE*49;
  float* DV   = W + o; o += (size_t)NE;
  float* LG   = W + o; o += (size_t)NE*8;
  float* MX   = W + o; o += (size_t)NN*8;
  float* DEN  = W + o; o += (size_t)NN*8;
  float* SG   = W + o; o += (size_t)NN*512;
  int* CNT = (int*)(W + o); o += NN;
  int* RP  = (int*)(W + o); o += NN + 1;
  int* EID = (int*)(W + o); o += NE;
  int* GS  = (int*)(W + o); o += NG + 1;
  int* CH  = (int*)(W + o); o += 4*NN;
  // bf16 transposed weights
  u16* WB = (u16*)(W + o);
  size_t wo = 0;
  u16* T_degw2 = WB + wo; wo += 16384;
  u16* T_degw3 = WB + wo; wo += 114688;
  u16* T_wst[3]; u16* T_wv[3]; u16* T_wp[3]; u16* T_rw2[3];
  for (int i = 0; i < 3; i++){ T_wst[i] = WB + wo; wo += 32768; }   // [256][128]
  for (int i = 0; i < 3; i++){ T_wv[i] = WB + wo; wo += 16384; }
  for (int i = 0; i < 3; i++){ T_wp[i] = WB + wo; wo += 16384; }
  for (int i = 0; i < 3; i++){ T_rw2[i] = WB + wo; wo += 16384; }
  u16* T_f1[2]; u16* T_f2[2];
  for (int i = 0; i < 2; i++){ T_f1[i] = WB + wo; wo += 65536; }
  for (int i = 0; i < 2; i++){ T_f2[i] = WB + wo; wo += 65536; }
  (void)ws_size; (void)in_sizes; (void)n_in; (void)out_size;

  u16*  XSTw = (u16*)XSTf;                        // [NN][29][256] bf16
  float* RADD = Hb;                               // E*896 = 11.0M <= Hb (12.85M); free before layers
  float* AG   = HR;
  float* OR_  = Hb;                               // latent proj out
  u16*  F1B   = (u16*)HR;                         // 50176*512 u16 = 25.7MB <= HR+XSTf (15.2M float-slots)

  // ---- all weight casts in one launch ----
  {
    CastJobs J;
    int idx = 0, acc = 0;
    auto add = [&](const float* s, u16* d, int K, int N){
      J.src[idx] = s; J.dst[idx] = d; J.K[idx] = K; J.N[idx] = N; J.start[idx] = acc;
      acc += K*N; idx++;
    };
    add(deg_w2, T_degw2, 128, 128);
    add(deg_w3, T_degw3, 128, 896);
    for (int i = 0; i < 3; i++){
      add((i < 2) ? w_src  + (size_t)i*16384 : lw_src,  T_wst[i],          128, 128);
      add((i < 2) ? w_tgt  + (size_t)i*16384 : lw_tgt,  T_wst[i] + 16384,  128, 128);
      add((i < 2) ? w_val  + (size_t)i*16384 : lw_val,  T_wv[i], 128, 128);
      add((i < 2) ? w_proj + (size_t)i*16384 : lw_proj, T_wp[i], 128, 128);
      add((i < 2) ? rad_w2 + (size_t)i*16384 : lrad_w2, T_rw2[i], 128, 128);
    }
    for (int i = 0; i < 2; i++){
      add(ffn_w1 + (size_t)i*65536, T_f1[i], 128, 512);
      add(ffn_w2 + (size_t)i*65536, T_f2[i], 512, 128);
    }
    J.start[idx] = acc; J.total = acc;
    k_castall<<<(acc + 255)/256, 256, 0, stream>>>(J);
  }

  // CSR + groups
  k_hist4<<<1, 1024, 0, stream>>>(dstp, CNT, CH);
  k_scan2<<<1, 1024, 0, stream>>>(CNT, RP);
  k_fillw4<<<NN, 256, 0, stream>>>(dstp, RP, CH, EID);
  k_gstart<<<1, 32, 0, stream>>>(batch, GS);

  // geometry
  k_geom<<<48, 256, 0, stream>>>(evec, Yb, DV);

  // degree embedding MLP: 600->128 (silu) -> 128 (silu) -> 896
  k_rad1<<<NE, 128, 0, stream>>>(DV, deg_w1, deg_b1, R1);
  k_mgemm<0,1,2><<<dim3(1, NE/64), 256, 0, stream>>>(R1, T_degw2, deg_b2, R2, NE, 128, 128, 128, nullptr);
  k_mgemm<0,0,2><<<dim3(7, NE/64), 256, 0, stream>>>(R2, T_degw3, nullptr, RADD, NE, 896, 128, 128, nullptr);
  k_init<<<NN, 128, 0, stream>>>(pos, table, Yb, RADD, RP, EID, X);

  for (int i = 0; i < 3; i++){
    const float* nw  = (i < 2) ? attn_nw + (size_t)i*896   : fin_nw;
    const float* rw1 = (i < 2) ? rad_w1 + (size_t)i*76800 : lrad_w1;
    const float* rb1 = (i < 2) ? rad_b1 + (size_t)i*128   : lrad_b1;
    const float* av  = (i < 2) ? avec   + (size_t)i*128   : lavec;

    k_rmsnormR<<<NN, 128, 0, stream>>>(X, nw, HR);
    // combined XS|XT projection, bf16 output
    k_mgemm<0,6,4><<<dim3(1, NN*NRr/64), 256, 0, stream>>>(HR, T_wst[i], nullptr, XSTw, NN*NRr, 256, 128, 128, nullptr);
    k_rad1<<<NE, 128, 0, stream>>>(DV, rw1, rb1, R1);
    k_mgemm<0,0,2><<<dim3(1, NE/64), 256, 0, stream>>>(R1, T_rw2[i], nullptr, R2, NE, 128, 128, 128, nullptr);
    k_logits<<<(NE*8 + 255)/256, 256, 0, stream>>>(XSTw, R2, av, srcp, dstp, LG);
    k_softmax<<<(NN*8 + 255)/256, 256, 0, stream>>>(LG, RP, EID, MX, DEN);
    // fused V + aggregation
    k_vagg<<<NN, 256, 0, stream>>>(XSTw, R2, T_wv[i], LG, MX, DEN, RP, EID, srcp, AG);
    if (i < 2){
      // projection with fused scatter-accumulate into X
      k_mgemm<0,3,2><<<dim3(1, NN*NRr/64), 256, 0, stream>>>(AG, T_wp[i], nullptr, X, NN*NRr, 128, 128, 128, nullptr);
      // FFN: h_gated[n,k,:] = (x@w1)[n,k,:] * sigmoid((x@w1)[n,0,:])  [silu(s)=s*sigmoid(s)]
      k_rmsnorm<<<NN, 128, 0, stream>>>(X, ffn_nw + (size_t)i*896, Hb);
      k_mgemm<0,4,4><<<dim3(2, NN/64), 256, 0, stream>>>(Hb, T_f1[i], nullptr, SG, NN, 512, 128, NCO*CD, nullptr);
      for (int half = 0; half < 2; half++){
        int n0 = half*(NN/2);
        int Mh = (NN/2)*NCO;   // 50176
        k_mgemm<0,5,4><<<dim3(2, Mh/64), 256, 0, stream>>>(Hb + (size_t)n0*NCO*CD, T_f1[i], nullptr, F1B,
                                                           Mh, 512, 128, 128, SG + (size_t)n0*512);
        k_mgemm<2,2,2><<<dim3(1, Mh/64), 256, 0, stream>>>(F1B, T_f2[i], nullptr, X + (size_t)n0*NCO*CD,
                                                           Mh, 128, 512, 512, nullptr);
      }
    } else {
      k_mgemm<0,0,2><<<dim3(1, NN*NRr/64), 256, 0, stream>>>(AG, T_wp[i], nullptr, OR_, NN*NRr, 128, 128, 128, nullptr);
      k_pool<<<(NG*NCO*CD + 255)/256, 256, 0, stream>>>(OR_, GS, (float*)d_out);
    }
  }
}